// Round 1
// baseline (509.360 us; speedup 1.0000x reference)
//
#include <hip/hip_runtime.h>

#define B_ 256
#define T_ 128
#define D_ 768
#define K_ 74
#define C_ 128
#define TK_ 9472      // T_*K_
#define BT_ 32768     // B_*T_
#define EMS_ 18944    // B_*K_  (em time-slice stride)

// ---------------- K1: logits = feats @ W1 + b1  (M=32768, N=74(pad80), K=768)
__global__ __launch_bounds__(256) void gemm_logits(const float* __restrict__ feats,
    const float* __restrict__ W1, const float* __restrict__ b1, float* __restrict__ logits)
{
    __shared__ float As[64][68];   // transposed: As[kk][row], 272B rows -> 16B aligned
    __shared__ float Bs[64][80];
    int tid = threadIdx.x;
    int tx = tid & 15, ty = tid >> 4;
    int r0 = blockIdx.x * 64;
    float acc[4][5] = {};
    for (int k0 = 0; k0 < 768; k0 += 64) {
        #pragma unroll
        for (int it = 0; it < 16; ++it) {
            int lin = it * 256 + tid;
            int r = lin >> 6, kk = lin & 63;
            As[kk][r] = feats[(r0 + r) * 768 + k0 + kk];
        }
        #pragma unroll
        for (int it = 0; it < 20; ++it) {
            int lin = it * 256 + tid;
            int kk = lin / 80, c = lin - kk * 80;
            Bs[kk][c] = (c < 74) ? W1[(k0 + kk) * 74 + c] : 0.f;
        }
        __syncthreads();
        for (int kk = 0; kk < 64; ++kk) {
            float4 a = *(const float4*)&As[kk][4 * tx];
            float bv[5];
            #pragma unroll
            for (int j = 0; j < 5; ++j) bv[j] = Bs[kk][5 * ty + j];
            const float* ap = (const float*)&a;
            #pragma unroll
            for (int i = 0; i < 4; ++i)
                #pragma unroll
                for (int j = 0; j < 5; ++j) acc[i][j] += ap[i] * bv[j];
        }
        __syncthreads();
    }
    #pragma unroll
    for (int i = 0; i < 4; ++i) {
        int r = r0 + 4 * tx + i;
        #pragma unroll
        for (int j = 0; j < 5; ++j) {
            int c = 5 * ty + j;
            if (c < 74) logits[r * 74 + c] = acc[i][j] + b1[c];
        }
    }
}

// ---------------- K2: sim partials. sim[p][q] = sum_{j,k} logits[p,j,k]*c[q,j,k]
// grid 256 = jc(32) x mt(4) x nt(2); each block: 64p x 64q over 4 j's (inner 296)
__global__ __launch_bounds__(256) void sim_partial(const float* __restrict__ logits,
    const float* __restrict__ cache, float* __restrict__ part)
{
    __shared__ float As[74][68];
    __shared__ float Bs[74][68];
    int tid = threadIdx.x;
    int tx = tid & 15, ty = tid >> 4;
    int bid = blockIdx.x;
    int jc = bid >> 3;
    int mt = (bid >> 1) & 3;
    int nt = bid & 1;
    int p0 = mt * 64, q0 = nt * 64;
    float acc[4][4] = {};
    for (int jj = 0; jj < 4; ++jj) {
        int j = jc * 4 + jj;
        for (int it = 0; it < 19; ++it) {
            int lin = it * 256 + tid;
            if (lin < 64 * 74) {
                int r = lin / 74, ik = lin - r * 74;
                As[ik][r] = logits[(p0 + r) * TK_ + j * 74 + ik];
                Bs[ik][r] = cache[(q0 + r) * TK_ + j * 74 + ik];
            }
        }
        __syncthreads();
        for (int ik = 0; ik < 74; ++ik) {
            float4 a = *(const float4*)&As[ik][4 * tx];
            float4 b = *(const float4*)&Bs[ik][4 * ty];
            const float* ap = (const float*)&a;
            const float* bp = (const float*)&b;
            #pragma unroll
            for (int i = 0; i < 4; ++i)
                #pragma unroll
                for (int q = 0; q < 4; ++q) acc[i][q] += ap[i] * bp[q];
        }
        __syncthreads();
    }
    #pragma unroll
    for (int i = 0; i < 4; ++i)
        #pragma unroll
        for (int q = 0; q < 4; ++q)
            part[jc * (B_ * C_) + (p0 + 4 * tx + i) * C_ + q0 + 4 * ty + q] = acc[i][q];
}

__global__ void sim_reduce(const float* __restrict__ part, float* __restrict__ sim)
{
    int idx = blockIdx.x * 256 + threadIdx.x;
    float s = 0.f;
    for (int jc = 0; jc < 32; ++jc) s += part[jc * (B_ * C_) + idx];
    sim[idx] = s;
}

__global__ void softmax128(const float* __restrict__ sim, float* __restrict__ p)
{
    __shared__ float red[128];
    int q = threadIdx.x, row = blockIdx.x;
    float v = sim[row * 128 + q];
    red[q] = v; __syncthreads();
    for (int s = 64; s > 0; s >>= 1) { if (q < s) red[q] = fmaxf(red[q], red[q + s]); __syncthreads(); }
    float m = red[0]; __syncthreads();
    float e = expf(v - m);
    red[q] = e; __syncthreads();
    for (int s = 64; s > 0; s >>= 1) { if (q < s) red[q] += red[q + s]; __syncthreads(); }
    float sum = red[0];
    p[row * 128 + q] = e / sum;
}

// ---------------- K4a: y = logits + 0.5*(p @ c_r)   (M=256, N=9472, K=128)
__global__ __launch_bounds__(256) void gemm_h_y(const float* __restrict__ pmat,
    const float* __restrict__ cache, const float* __restrict__ logits, float* __restrict__ y)
{
    __shared__ float As[128][68];
    __shared__ float Bs[128][68];
    int tid = threadIdx.x;
    int tx = tid & 15, ty = tid >> 4;
    int mt = blockIdx.x / 148, nt = blockIdx.x - mt * 148;
    int r0 = mt * 64, n0 = nt * 64;
    #pragma unroll
    for (int it = 0; it < 32; ++it) {
        int lin = it * 256 + tid;
        int r = lin >> 7, kk = lin & 127;
        As[kk][r] = pmat[(r0 + r) * 128 + kk];
    }
    #pragma unroll
    for (int it = 0; it < 32; ++it) {
        int lin = it * 256 + tid;
        int kk = lin >> 6, c = lin & 63;
        Bs[kk][c] = cache[kk * TK_ + n0 + c];
    }
    __syncthreads();
    float acc[4][4] = {};
    for (int kk = 0; kk < 128; ++kk) {
        float4 a = *(const float4*)&As[kk][4 * tx];
        float4 b = *(const float4*)&Bs[kk][4 * ty];
        const float* ap = (const float*)&a;
        const float* bp = (const float*)&b;
        #pragma unroll
        for (int i = 0; i < 4; ++i)
            #pragma unroll
            for (int j = 0; j < 4; ++j) acc[i][j] += ap[i] * bp[j];
    }
    #pragma unroll
    for (int i = 0; i < 4; ++i) {
        int r = r0 + 4 * tx + i;
        #pragma unroll
        for (int j = 0; j < 4; ++j) {
            int n = n0 + 4 * ty + j;
            y[r * TK_ + n] = logits[r * TK_ + n] + 0.5f * acc[i][j];
        }
    }
}

// ---------------- K4b: em[t][b][k'] = (y @ W2 + b2) transposed write  (M=32768,N=74,K=74)
__global__ __launch_bounds__(256) void gemm_em(const float* __restrict__ y,
    const float* __restrict__ W2, const float* __restrict__ b2, float* __restrict__ em)
{
    __shared__ float As[74][68];
    __shared__ float Bs[74][80];
    int tid = threadIdx.x;
    int tx = tid & 15, ty = tid >> 4;
    int r0 = blockIdx.x * 64;
    for (int it = 0; it < 19; ++it) {
        int lin = it * 256 + tid;
        if (lin < 64 * 74) {
            int r = lin / 74, kk = lin - r * 74;
            As[kk][r] = y[(r0 + r) * 74 + kk];
        }
    }
    for (int it = 0; it < 24; ++it) {
        int lin = it * 256 + tid;
        if (lin < 74 * 80) {
            int kk = lin / 80, c = lin - kk * 80;
            Bs[kk][c] = (c < 74) ? W2[kk * 74 + c] : 0.f;
        }
    }
    __syncthreads();
    float acc[4][5] = {};
    for (int kk = 0; kk < 74; ++kk) {
        float4 a = *(const float4*)&As[kk][4 * tx];
        float bv[5];
        #pragma unroll
        for (int j = 0; j < 5; ++j) bv[j] = Bs[kk][5 * ty + j];
        const float* ap = (const float*)&a;
        #pragma unroll
        for (int i = 0; i < 4; ++i)
            #pragma unroll
            for (int j = 0; j < 5; ++j) acc[i][j] += ap[i] * bv[j];
    }
    #pragma unroll
    for (int i = 0; i < 4; ++i) {
        int r = r0 + 4 * tx + i;
        int b = r >> 7, t = r & 127;
        #pragma unroll
        for (int j = 0; j < 5; ++j) {
            int c = 5 * ty + j;
            if (c < 74) em[t * EMS_ + b * 74 + c] = acc[i][j] + b2[c];
        }
    }
}

// ---------------- K5: fused CRF scans. blocks 0..255 Viterbi(+backtrace), 256..511 normalizer.
__global__ __launch_bounds__(256) void crf_scan(const float* __restrict__ em,
    const int* __restrict__ mask_, const float* __restrict__ startv,
    const float* __restrict__ endv, const float* __restrict__ trans,
    float* __restrict__ out_tags, float* __restrict__ den)
{
    __shared__ float transS[74 * 74];
    __shared__ float scoreS[2][80];
    __shared__ float pv[3][74];
    __shared__ int   pi[3][74];
    __shared__ unsigned char histS[127 * 74];
    __shared__ float Ms[2];
    int tid = threadIdx.x;
    bool isV = blockIdx.x < 256;
    int b = isV ? blockIdx.x : (blockIdx.x - 256);

    for (int i = tid; i < 74 * 74; i += 256) transS[i] = trans[i];
    if (tid >= 74 && tid < 80) { scoreS[0][tid] = 0.f; scoreS[1][tid] = 0.f; }
    if (tid < 74) scoreS[0][tid] = startv[tid] + em[b * 74 + tid];
    __syncthreads();

    int ch = tid / 74;                 // 0..2 active (tid<222), 3 = idle
    int kp = tid - ch * 74;
    int cbase = (ch == 0) ? 0 : (ch == 1 ? 25 : 50);
    int cend  = (ch == 0) ? 25 : (ch == 1 ? 50 : 74);
    float tr[25];
    if (tid < 222) {
        #pragma unroll
        for (int j = 0; j < 25; ++j) {
            int kk = cbase + j;
            tr[j] = (kk < cend) ? transS[kk * 74 + kp] : -1.0e30f;
        }
    }
    int cur = 0;

    if (isV) {
        for (int t = 1; t < 128; ++t) {
            float e = (tid < 74) ? em[t * EMS_ + b * 74 + tid] : 0.f;
            if (tid < 222) {
                float m = -3.0e38f; int mi = cbase;
                #pragma unroll
                for (int j = 0; j < 25; ++j) {
                    float v = scoreS[cur][cbase + j] + tr[j];
                    if (v > m) { m = v; mi = cbase + j; }
                }
                pv[ch][kp] = m; pi[ch][kp] = mi;
            }
            __syncthreads();
            if (tid < 74) {
                float m0 = pv[0][tid]; int i0 = pi[0][tid];
                if (pv[1][tid] > m0) { m0 = pv[1][tid]; i0 = pi[1][tid]; }
                if (pv[2][tid] > m0) { m0 = pv[2][tid]; i0 = pi[2][tid]; }
                histS[(t - 1) * 74 + tid] = (unsigned char)i0;
                int mk = mask_[b * 128 + t];
                scoreS[cur ^ 1][tid] = mk ? (m0 + e) : scoreS[cur][tid];
            }
            __syncthreads();
            cur ^= 1;
        }
        if (tid == 0) {
            float bm = scoreS[cur][0] + endv[0]; int bi = 0;
            for (int k = 1; k < 74; ++k) {
                float v = scoreS[cur][k] + endv[k];
                if (v > bm) { bm = v; bi = k; }
            }
            int curk = bi;
            out_tags[b * 128 + 127] = (float)bi;
            for (int ti = 126; ti >= 0; --ti) {
                int mk = mask_[b * 128 + ti + 1];
                curk = mk ? (int)histS[ti * 74 + curk] : bi;
                out_tags[b * 128 + ti] = (float)curk;
            }
        }
    } else {
        float v0 = (tid < 74) ? scoreS[0][tid] : -3.0e38f;
        float M;
        if (tid < 128) {
            #pragma unroll
            for (int off = 32; off > 0; off >>= 1) v0 = fmaxf(v0, __shfl_xor(v0, off));
            if ((tid & 63) == 0) Ms[tid >> 6] = v0;
        }
        __syncthreads();
        M = fmaxf(Ms[0], Ms[1]);
        for (int t = 1; t < 128; ++t) {
            float e = (tid < 74) ? em[t * EMS_ + b * 74 + tid] : 0.f;
            if (tid < 222) {
                float s = 0.f;
                #pragma unroll
                for (int j = 0; j < 25; ++j)
                    s += __expf(scoreS[cur][cbase + j] + tr[j] - M);
                pv[ch][kp] = s;
            }
            __syncthreads();
            if (tid < 74) {
                float sum = pv[0][tid] + pv[1][tid] + pv[2][tid];
                float nxt = M + logf(sum) + e;
                int mk = mask_[b * 128 + t];
                scoreS[cur ^ 1][tid] = mk ? nxt : scoreS[cur][tid];
            }
            __syncthreads();
            cur ^= 1;
            float v = (tid < 74) ? scoreS[cur][tid] : -3.0e38f;
            if (tid < 128) {
                #pragma unroll
                for (int off = 32; off > 0; off >>= 1) v = fmaxf(v, __shfl_xor(v, off));
                if ((tid & 63) == 0) Ms[tid >> 6] = v;
            }
            __syncthreads();
            M = fmaxf(Ms[0], Ms[1]);
        }
        if (tid == 0) {
            float m = -3.0e38f;
            for (int k = 0; k < 74; ++k) m = fmaxf(m, scoreS[cur][k] + endv[k]);
            float s = 0.f;
            for (int k = 0; k < 74; ++k) s += __expf(scoreS[cur][k] + endv[k] - m);
            den[b] = m + logf(s);
        }
    }
}

// ---------------- K6: CRF score + loss
__global__ void loss_kernel(const float* __restrict__ em, const int* __restrict__ labels,
    const int* __restrict__ mask_, const float* __restrict__ startv, const float* __restrict__ endv,
    const float* __restrict__ trans, const float* __restrict__ den, float* __restrict__ out_loss)
{
    __shared__ float red[256];
    int b = threadIdx.x;
    int l0 = labels[b * 128];
    float sc = startv[l0] + em[b * 74 + l0];
    int prev = l0;
    int msum = mask_[b * 128];
    for (int t = 1; t < 128; ++t) {
        int c = labels[b * 128 + t];
        int mk = mask_[b * 128 + t];
        msum += mk;
        float add = trans[prev * 74 + c] + em[t * EMS_ + b * 74 + c];
        sc += mk ? add : 0.f;
        prev = c;
    }
    int send = msum - 1;
    int last = labels[b * 128 + send];
    float num = sc + endv[last];
    red[b] = num - den[b];
    __syncthreads();
    for (int s = 128; s > 0; s >>= 1) { if (b < s) red[b] += red[b + s]; __syncthreads(); }
    if (b == 0) out_loss[0] = -(red[0] / 256.f);
}

extern "C" void kernel_launch(void* const* d_in, const int* in_sizes, int n_in,
                              void* d_out, int out_size, void* d_ws, size_t ws_size,
                              hipStream_t stream)
{
    const float* feats  = (const float*)d_in[0];
    const int*   amask  = (const int*)d_in[1];
    const int*   labels = (const int*)d_in[2];
    const float* cache  = (const float*)d_in[3];
    const float* W1     = (const float*)d_in[4];
    const float* b1     = (const float*)d_in[5];
    const float* W2     = (const float*)d_in[6];
    const float* b2     = (const float*)d_in[7];
    const float* startv = (const float*)d_in[8];
    const float* endv   = (const float*)d_in[9];
    const float* trans  = (const float*)d_in[10];

    float* ws     = (float*)d_ws;
    float* logits = ws;                 // 2,424,832
    float* y      = ws + 2424832;       // 2,424,832
    float* em     = ws + 4849664;       // 2,424,832
    float* part   = ws + 7274496;       // 1,048,576
    float* sim    = ws + 8323072;       // 32,768
    float* p      = ws + 8355840;       // 32,768
    float* den    = ws + 8388608;       // 256
    float* out_tags = (float*)d_out;
    float* out_loss = (float*)d_out + 32768;

    hipLaunchKernelGGL(gemm_logits, dim3(512), dim3(256), 0, stream, feats, W1, b1, logits);
    hipLaunchKernelGGL(sim_partial, dim3(256), dim3(256), 0, stream, logits, cache, part);
    hipLaunchKernelGGL(sim_reduce,  dim3(128), dim3(256), 0, stream, part, sim);
    hipLaunchKernelGGL(softmax128,  dim3(256), dim3(128), 0, stream, sim, p);
    hipLaunchKernelGGL(gemm_h_y,    dim3(592), dim3(256), 0, stream, p, cache, logits, y);
    hipLaunchKernelGGL(gemm_em,     dim3(512), dim3(256), 0, stream, y, W2, b2, em);
    hipLaunchKernelGGL(crf_scan,    dim3(512), dim3(256), 0, stream, em, amask, startv, endv, trans, out_tags, den);
    hipLaunchKernelGGL(loss_kernel, dim3(1),   dim3(256), 0, stream, em, labels, amask, startv, endv, trans, den, out_loss);
}

// Round 2
// 448.489 us; speedup vs baseline: 1.1357x; 1.1357x over previous
//
#include <hip/hip_runtime.h>

#define B_ 256
#define T_ 128
#define D_ 768
#define K_ 74
#define C_ 128
#define TK_ 9472      // T_*K_
#define BT_ 32768     // B_*T_
#define EMS_ 18944    // B_*K_  (em time-slice stride)

// ---------------- K1: logits = feats @ W1 + b1  (M=32768, N=74, K=768)
// Row-per-thread: A streamed per-lane from global (no LDS), W1 chunk in LDS read
// as block-uniform broadcasts (conflict-free). Grid 512 = 128 row-blocks x 4 col-quarters.
__global__ __launch_bounds__(256) void gemm_logits(const float* __restrict__ feats,
    const float* __restrict__ W1, const float* __restrict__ b1, float* __restrict__ logits)
{
    __shared__ float Bs[64][20];
    int tid = threadIdx.x;
    int rb = blockIdx.x >> 2;
    int nq = blockIdx.x & 3;
    int r  = rb * 256 + tid;           // one output row per thread
    int c0 = nq * 19;
    const float* frow = feats + (size_t)r * 768;
    float acc[20];
    #pragma unroll
    for (int j = 0; j < 20; ++j) acc[j] = 0.f;

    for (int k0 = 0; k0 < 768; k0 += 64) {
        #pragma unroll
        for (int it = 0; it < 5; ++it) {
            int lin = it * 256 + tid;           // 0..1279
            int kk = lin / 20, j = lin - kk * 20;
            int c = c0 + j;
            Bs[kk][j] = (j < 19 && c < 74) ? W1[(k0 + kk) * 74 + c] : 0.f;
        }
        __syncthreads();
        for (int kk = 0; kk < 64; kk += 4) {
            float4 a = *(const float4*)(frow + k0 + kk);
            const float* ap = (const float*)&a;
            #pragma unroll
            for (int u = 0; u < 4; ++u) {
                #pragma unroll
                for (int jb = 0; jb < 5; ++jb) {
                    float4 bv = *(const float4*)&Bs[kk + u][jb * 4];
                    acc[jb * 4 + 0] += ap[u] * bv.x;
                    acc[jb * 4 + 1] += ap[u] * bv.y;
                    acc[jb * 4 + 2] += ap[u] * bv.z;
                    acc[jb * 4 + 3] += ap[u] * bv.w;
                }
            }
        }
        __syncthreads();
    }
    #pragma unroll
    for (int j = 0; j < 19; ++j) {
        int c = c0 + j;
        if (c < 74) logits[(size_t)r * 74 + c] = acc[j] + b1[c];
    }
}

// ---------------- K2: sim partials. sim[p][q] = sum_{j,k} logits[p,j,k]*c[q,j,k]
__global__ __launch_bounds__(256) void sim_partial(const float* __restrict__ logits,
    const float* __restrict__ cache, float* __restrict__ part)
{
    __shared__ float As[74][68];
    __shared__ float Bs[74][68];
    int tid = threadIdx.x;
    int tx = tid & 15, ty = tid >> 4;
    int bid = blockIdx.x;
    int jc = bid >> 3;
    int mt = (bid >> 1) & 3;
    int nt = bid & 1;
    int p0 = mt * 64, q0 = nt * 64;
    float acc[4][4] = {};
    for (int jj = 0; jj < 4; ++jj) {
        int j = jc * 4 + jj;
        for (int it = 0; it < 19; ++it) {
            int lin = it * 256 + tid;
            if (lin < 64 * 74) {
                int r = lin / 74, ik = lin - r * 74;
                As[ik][r] = logits[(p0 + r) * TK_ + j * 74 + ik];
                Bs[ik][r] = cache[(q0 + r) * TK_ + j * 74 + ik];
            }
        }
        __syncthreads();
        for (int ik = 0; ik < 74; ++ik) {
            float4 a = *(const float4*)&As[ik][4 * tx];
            float4 b = *(const float4*)&Bs[ik][4 * ty];
            const float* ap = (const float*)&a;
            const float* bp = (const float*)&b;
            #pragma unroll
            for (int i = 0; i < 4; ++i)
                #pragma unroll
                for (int q = 0; q < 4; ++q) acc[i][q] += ap[i] * bp[q];
        }
        __syncthreads();
    }
    #pragma unroll
    for (int i = 0; i < 4; ++i)
        #pragma unroll
        for (int q = 0; q < 4; ++q)
            part[jc * (B_ * C_) + (p0 + 4 * tx + i) * C_ + q0 + 4 * ty + q] = acc[i][q];
}

__global__ void sim_reduce(const float* __restrict__ part, float* __restrict__ sim)
{
    int idx = blockIdx.x * 256 + threadIdx.x;
    float s = 0.f;
    for (int jc = 0; jc < 32; ++jc) s += part[jc * (B_ * C_) + idx];
    sim[idx] = s;
}

__global__ void softmax128(const float* __restrict__ sim, float* __restrict__ p)
{
    __shared__ float red[128];
    int q = threadIdx.x, row = blockIdx.x;
    float v = sim[row * 128 + q];
    red[q] = v; __syncthreads();
    for (int s = 64; s > 0; s >>= 1) { if (q < s) red[q] = fmaxf(red[q], red[q + s]); __syncthreads(); }
    float m = red[0]; __syncthreads();
    float e = expf(v - m);
    red[q] = e; __syncthreads();
    for (int s = 64; s > 0; s >>= 1) { if (q < s) red[q] += red[q + s]; __syncthreads(); }
    float sum = red[0];
    p[row * 128 + q] = e / sum;
}

// ---------------- K4a: y = logits + 0.5*(p @ c_r)   (M=256, N=9472, K=128)
__global__ __launch_bounds__(256) void gemm_h_y(const float* __restrict__ pmat,
    const float* __restrict__ cache, const float* __restrict__ logits, float* __restrict__ y)
{
    __shared__ float As[128][68];
    __shared__ float Bs[128][68];
    int tid = threadIdx.x;
    int tx = tid & 15, ty = tid >> 4;
    int mt = blockIdx.x / 148, nt = blockIdx.x - mt * 148;
    int r0 = mt * 64, n0 = nt * 64;
    #pragma unroll
    for (int it = 0; it < 32; ++it) {
        int lin = it * 256 + tid;
        int r = lin >> 7, kk = lin & 127;
        As[kk][r] = pmat[(r0 + r) * 128 + kk];
    }
    #pragma unroll
    for (int it = 0; it < 32; ++it) {
        int lin = it * 256 + tid;
        int kk = lin >> 6, c = lin & 63;
        Bs[kk][c] = cache[kk * TK_ + n0 + c];
    }
    __syncthreads();
    float acc[4][4] = {};
    for (int kk = 0; kk < 128; ++kk) {
        float4 a = *(const float4*)&As[kk][4 * tx];
        float4 b = *(const float4*)&Bs[kk][4 * ty];
        const float* ap = (const float*)&a;
        const float* bp = (const float*)&b;
        #pragma unroll
        for (int i = 0; i < 4; ++i)
            #pragma unroll
            for (int j = 0; j < 4; ++j) acc[i][j] += ap[i] * bp[j];
    }
    #pragma unroll
    for (int i = 0; i < 4; ++i) {
        int r = r0 + 4 * tx + i;
        #pragma unroll
        for (int j = 0; j < 4; ++j) {
            int n = n0 + 4 * ty + j;
            y[r * TK_ + n] = logits[r * TK_ + n] + 0.5f * acc[i][j];
        }
    }
}

// ---------------- K4b: em = (y @ W2 + b2) transposed write (M=32768, N=74, K=74)
// Row-per-thread, W2 fully staged in LDS (broadcast reads). Grid 512 = 128 x 4.
__global__ __launch_bounds__(256) void gemm_em(const float* __restrict__ y,
    const float* __restrict__ W2, const float* __restrict__ b2, float* __restrict__ em)
{
    __shared__ float Bs[74][20];
    int tid = threadIdx.x;
    int rb = blockIdx.x >> 2;
    int nq = blockIdx.x & 3;
    int r  = rb * 256 + tid;
    int c0 = nq * 19;
    #pragma unroll
    for (int it = 0; it < 6; ++it) {
        int lin = it * 256 + tid;           // 0..1535, need 1480
        if (lin < 74 * 20) {
            int kk = lin / 20, j = lin - kk * 20;
            int c = c0 + j;
            Bs[kk][j] = (j < 19 && c < 74) ? W2[kk * 74 + c] : 0.f;
        }
    }
    __syncthreads();
    const float2* yrow = (const float2*)(y + (size_t)r * 74);
    float acc[20];
    #pragma unroll
    for (int j = 0; j < 20; ++j) acc[j] = 0.f;
    for (int kb = 0; kb < 37; ++kb) {
        float2 a = yrow[kb];
        const float* ap = (const float*)&a;
        #pragma unroll
        for (int u = 0; u < 2; ++u) {
            int kk = 2 * kb + u;
            #pragma unroll
            for (int jb = 0; jb < 5; ++jb) {
                float4 bv = *(const float4*)&Bs[kk][jb * 4];
                acc[jb * 4 + 0] += ap[u] * bv.x;
                acc[jb * 4 + 1] += ap[u] * bv.y;
                acc[jb * 4 + 2] += ap[u] * bv.z;
                acc[jb * 4 + 3] += ap[u] * bv.w;
            }
        }
    }
    int b = r >> 7, t = r & 127;
    #pragma unroll
    for (int j = 0; j < 19; ++j) {
        int c = c0 + j;
        if (c < 74) em[t * EMS_ + b * 74 + c] = acc[j] + b2[c];
    }
}

// ---------------- K5: fused CRF scans. blocks 0..255 Viterbi(+backtrace), 256..511 normalizer.
__global__ __launch_bounds__(256) void crf_scan(const float* __restrict__ em,
    const int* __restrict__ mask_, const float* __restrict__ startv,
    const float* __restrict__ endv, const float* __restrict__ trans,
    float* __restrict__ out_tags, float* __restrict__ den)
{
    __shared__ float transS[74 * 74];
    __shared__ float scoreS[2][80];
    __shared__ float pv[3][74];
    __shared__ int   pi[3][74];
    __shared__ unsigned char histS[127 * 74];
    __shared__ float Ms[2];
    int tid = threadIdx.x;
    bool isV = blockIdx.x < 256;
    int b = isV ? blockIdx.x : (blockIdx.x - 256);

    for (int i = tid; i < 74 * 74; i += 256) transS[i] = trans[i];
    if (tid >= 74 && tid < 80) { scoreS[0][tid] = 0.f; scoreS[1][tid] = 0.f; }
    if (tid < 74) scoreS[0][tid] = startv[tid] + em[b * 74 + tid];
    __syncthreads();

    int ch = tid / 74;                 // 0..2 active (tid<222), 3 = idle
    int kp = tid - ch * 74;
    int cbase = (ch == 0) ? 0 : (ch == 1 ? 25 : 50);
    int cend  = (ch == 0) ? 25 : (ch == 1 ? 50 : 74);
    float tr[25];
    if (tid < 222) {
        #pragma unroll
        for (int j = 0; j < 25; ++j) {
            int kk = cbase + j;
            tr[j] = (kk < cend) ? transS[kk * 74 + kp] : -1.0e30f;
        }
    }
    int cur = 0;

    if (isV) {
        for (int t = 1; t < 128; ++t) {
            float e = (tid < 74) ? em[t * EMS_ + b * 74 + tid] : 0.f;
            if (tid < 222) {
                float m = -3.0e38f; int mi = cbase;
                #pragma unroll
                for (int j = 0; j < 25; ++j) {
                    float v = scoreS[cur][cbase + j] + tr[j];
                    if (v > m) { m = v; mi = cbase + j; }
                }
                pv[ch][kp] = m; pi[ch][kp] = mi;
            }
            __syncthreads();
            if (tid < 74) {
                float m0 = pv[0][tid]; int i0 = pi[0][tid];
                if (pv[1][tid] > m0) { m0 = pv[1][tid]; i0 = pi[1][tid]; }
                if (pv[2][tid] > m0) { m0 = pv[2][tid]; i0 = pi[2][tid]; }
                histS[(t - 1) * 74 + tid] = (unsigned char)i0;
                int mk = mask_[b * 128 + t];
                scoreS[cur ^ 1][tid] = mk ? (m0 + e) : scoreS[cur][tid];
            }
            __syncthreads();
            cur ^= 1;
        }
        if (tid == 0) {
            float bm = scoreS[cur][0] + endv[0]; int bi = 0;
            for (int k = 1; k < 74; ++k) {
                float v = scoreS[cur][k] + endv[k];
                if (v > bm) { bm = v; bi = k; }
            }
            int curk = bi;
            out_tags[b * 128 + 127] = (float)bi;
            for (int ti = 126; ti >= 0; --ti) {
                int mk = mask_[b * 128 + ti + 1];
                curk = mk ? (int)histS[ti * 74 + curk] : bi;
                out_tags[b * 128 + ti] = (float)curk;
            }
        }
    } else {
        float v0 = (tid < 74) ? scoreS[0][tid] : -3.0e38f;
        float M;
        if (tid < 128) {
            #pragma unroll
            for (int off = 32; off > 0; off >>= 1) v0 = fmaxf(v0, __shfl_xor(v0, off));
            if ((tid & 63) == 0) Ms[tid >> 6] = v0;
        }
        __syncthreads();
        M = fmaxf(Ms[0], Ms[1]);
        for (int t = 1; t < 128; ++t) {
            float e = (tid < 74) ? em[t * EMS_ + b * 74 + tid] : 0.f;
            if (tid < 222) {
                float s = 0.f;
                #pragma unroll
                for (int j = 0; j < 25; ++j)
                    s += __expf(scoreS[cur][cbase + j] + tr[j] - M);
                pv[ch][kp] = s;
            }
            __syncthreads();
            if (tid < 74) {
                float sum = pv[0][tid] + pv[1][tid] + pv[2][tid];
                float nxt = M + logf(sum) + e;
                int mk = mask_[b * 128 + t];
                scoreS[cur ^ 1][tid] = mk ? nxt : scoreS[cur][tid];
            }
            __syncthreads();
            cur ^= 1;
            float v = (tid < 74) ? scoreS[cur][tid] : -3.0e38f;
            if (tid < 128) {
                #pragma unroll
                for (int off = 32; off > 0; off >>= 1) v = fmaxf(v, __shfl_xor(v, off));
                if ((tid & 63) == 0) Ms[tid >> 6] = v;
            }
            __syncthreads();
            M = fmaxf(Ms[0], Ms[1]);
        }
        if (tid == 0) {
            float m = -3.0e38f;
            for (int k = 0; k < 74; ++k) m = fmaxf(m, scoreS[cur][k] + endv[k]);
            float s = 0.f;
            for (int k = 0; k < 74; ++k) s += __expf(scoreS[cur][k] + endv[k] - m);
            den[b] = m + logf(s);
        }
    }
}

// ---------------- K6: CRF score + loss
__global__ void loss_kernel(const float* __restrict__ em, const int* __restrict__ labels,
    const int* __restrict__ mask_, const float* __restrict__ startv, const float* __restrict__ endv,
    const float* __restrict__ trans, const float* __restrict__ den, float* __restrict__ out_loss)
{
    __shared__ float red[256];
    int b = threadIdx.x;
    int l0 = labels[b * 128];
    float sc = startv[l0] + em[b * 74 + l0];
    int prev = l0;
    int msum = mask_[b * 128];
    for (int t = 1; t < 128; ++t) {
        int c = labels[b * 128 + t];
        int mk = mask_[b * 128 + t];
        msum += mk;
        float add = trans[prev * 74 + c] + em[t * EMS_ + b * 74 + c];
        sc += mk ? add : 0.f;
        prev = c;
    }
    int send = msum - 1;
    int last = labels[b * 128 + send];
    float num = sc + endv[last];
    red[b] = num - den[b];
    __syncthreads();
    for (int s = 128; s > 0; s >>= 1) { if (b < s) red[b] += red[b + s]; __syncthreads(); }
    if (b == 0) out_loss[0] = -(red[0] / 256.f);
}

extern "C" void kernel_launch(void* const* d_in, const int* in_sizes, int n_in,
                              void* d_out, int out_size, void* d_ws, size_t ws_size,
                              hipStream_t stream)
{
    const float* feats  = (const float*)d_in[0];
    const int*   amask  = (const int*)d_in[1];
    const int*   labels = (const int*)d_in[2];
    const float* cache  = (const float*)d_in[3];
    const float* W1     = (const float*)d_in[4];
    const float* b1     = (const float*)d_in[5];
    const float* W2     = (const float*)d_in[6];
    const float* b2     = (const float*)d_in[7];
    const float* startv = (const float*)d_in[8];
    const float* endv   = (const float*)d_in[9];
    const float* trans  = (const float*)d_in[10];

    float* ws     = (float*)d_ws;
    float* logits = ws;                 // 2,424,832
    float* y      = ws + 2424832;       // 2,424,832
    float* em     = ws + 4849664;       // 2,424,832
    float* part   = ws + 7274496;       // 1,048,576
    float* sim    = ws + 8323072;       // 32,768
    float* p      = ws + 8355840;       // 32,768
    float* den    = ws + 8388608;       // 256
    float* out_tags = (float*)d_out;
    float* out_loss = (float*)d_out + 32768;

    hipLaunchKernelGGL(gemm_logits, dim3(512), dim3(256), 0, stream, feats, W1, b1, logits);
    hipLaunchKernelGGL(sim_partial, dim3(256), dim3(256), 0, stream, logits, cache, part);
    hipLaunchKernelGGL(sim_reduce,  dim3(128), dim3(256), 0, stream, part, sim);
    hipLaunchKernelGGL(softmax128,  dim3(256), dim3(128), 0, stream, sim, p);
    hipLaunchKernelGGL(gemm_h_y,    dim3(592), dim3(256), 0, stream, p, cache, logits, y);
    hipLaunchKernelGGL(gemm_em,     dim3(512), dim3(256), 0, stream, y, W2, b2, em);
    hipLaunchKernelGGL(crf_scan,    dim3(512), dim3(256), 0, stream, em, amask, startv, endv, trans, out_tags, den);
    hipLaunchKernelGGL(loss_kernel, dim3(1),   dim3(256), 0, stream, em, labels, amask, startv, endv, trans, den, out_loss);
}

// Round 3
// 342.514 us; speedup vs baseline: 1.4871x; 1.3094x over previous
//
#include <hip/hip_runtime.h>

#define B_ 256
#define T_ 128
#define D_ 768
#define K_ 74
#define C_ 128
#define TK_ 9472      // T_*K_
#define BT_ 32768     // B_*T_
#define EMS_ 18944    // B_*K_  (em time-slice stride)

// ---------------- K0: pad W1 -> W1q[4][768][20], W2 -> W2q[4][74][20] (quarter-planes, 16B aligned)
__global__ void pad_weights(const float* __restrict__ W1, const float* __restrict__ W2,
                            float* __restrict__ W1q, float* __restrict__ W2q)
{
    int idx = blockIdx.x * 256 + threadIdx.x;
    if (idx < 4 * 768 * 20) {
        int nq = idx / (768 * 20); int rem = idx - nq * (768 * 20);
        int k = rem / 20, j = rem - k * 20;
        int c = nq * 19 + j;
        W1q[idx] = (j < 19 && c < 74) ? W1[k * 74 + c] : 0.f;
    }
    if (idx < 4 * 74 * 20) {
        int nq = idx / (74 * 20); int rem = idx - nq * (74 * 20);
        int k = rem / 20, j = rem - k * 20;
        int c = nq * 19 + j;
        W2q[idx] = (j < 19 && c < 74) ? W2[k * 74 + c] : 0.f;
    }
}

// ---------------- K1: logits = feats @ W1 + b1  (M=32768, N=74, K=768)
// Row-per-thread; W1q read at uniform addresses -> SGPR (scalar pipe), zero LDS.
// XCD swizzle: all 4 col-quarters of a row range land on the same XCD's L2.
__global__ __launch_bounds__(256) void gemm_logits(const float* __restrict__ feats,
    const float* __restrict__ W1q, const float* __restrict__ b1, float* __restrict__ logits)
{
    int orig = blockIdx.x;                  // grid 512, divisible by 8
    int vb = (orig & 7) * 64 + (orig >> 3); // 64 consecutive virtual blocks per XCD
    int rb = vb >> 2, nq = vb & 3;
    int tid = threadIdx.x;
    int r = rb * 256 + tid;
    int c0 = nq * 19;
    const float* frow = feats + (size_t)r * 768;
    const float* wq = W1q + nq * (768 * 20);
    float acc[20];
    #pragma unroll
    for (int j = 0; j < 20; ++j) acc[j] = 0.f;

    for (int k0 = 0; k0 < 768; k0 += 16) {
        float4 a[4];
        #pragma unroll
        for (int q = 0; q < 4; ++q) a[q] = *(const float4*)(frow + k0 + 4 * q);
        #pragma unroll
        for (int u = 0; u < 16; ++u) {
            float av = ((const float*)a)[u];
            const float* wr = wq + (k0 + u) * 20;   // uniform -> s_load_dwordx4 x5
            #pragma unroll
            for (int j = 0; j < 20; ++j) acc[j] += av * wr[j];
        }
    }
    #pragma unroll
    for (int j = 0; j < 19; ++j) {
        int c = c0 + j;
        if (c < 74) logits[(size_t)r * 74 + c] = acc[j] + b1[c];
    }
}

// ---------------- K2: sim partials. sim[p][q] = sum_{j,k} logits[p,j,k]*c[q,j,k]
__global__ __launch_bounds__(256) void sim_partial(const float* __restrict__ logits,
    const float* __restrict__ cache, float* __restrict__ part)
{
    __shared__ float As[74][68];
    __shared__ float Bs[74][68];
    int tid = threadIdx.x;
    int tx = tid & 15, ty = tid >> 4;
    int bid = blockIdx.x;
    int jc = bid >> 3;
    int mt = (bid >> 1) & 3;
    int nt = bid & 1;
    int p0 = mt * 64, q0 = nt * 64;
    float acc[4][4] = {};
    for (int jj = 0; jj < 4; ++jj) {
        int j = jc * 4 + jj;
        for (int it = 0; it < 19; ++it) {
            int lin = it * 256 + tid;
            if (lin < 64 * 74) {
                int r = lin / 74, ik = lin - r * 74;
                As[ik][r] = logits[(p0 + r) * TK_ + j * 74 + ik];
                Bs[ik][r] = cache[(q0 + r) * TK_ + j * 74 + ik];
            }
        }
        __syncthreads();
        for (int ik = 0; ik < 74; ++ik) {
            float4 a = *(const float4*)&As[ik][4 * tx];
            float4 b = *(const float4*)&Bs[ik][4 * ty];
            const float* ap = (const float*)&a;
            const float* bp = (const float*)&b;
            #pragma unroll
            for (int i = 0; i < 4; ++i)
                #pragma unroll
                for (int q = 0; q < 4; ++q) acc[i][q] += ap[i] * bp[q];
        }
        __syncthreads();
    }
    #pragma unroll
    for (int i = 0; i < 4; ++i)
        #pragma unroll
        for (int q = 0; q < 4; ++q)
            part[jc * (B_ * C_) + (p0 + 4 * tx + i) * C_ + q0 + 4 * ty + q] = acc[i][q];
}

__global__ void sim_reduce(const float* __restrict__ part, float* __restrict__ sim)
{
    int idx = blockIdx.x * 256 + threadIdx.x;
    float s = 0.f;
    for (int jc = 0; jc < 32; ++jc) s += part[jc * (B_ * C_) + idx];
    sim[idx] = s;
}

__global__ void softmax128(const float* __restrict__ sim, float* __restrict__ p)
{
    __shared__ float red[128];
    int q = threadIdx.x, row = blockIdx.x;
    float v = sim[row * 128 + q];
    red[q] = v; __syncthreads();
    for (int s = 64; s > 0; s >>= 1) { if (q < s) red[q] = fmaxf(red[q], red[q + s]); __syncthreads(); }
    float m = red[0]; __syncthreads();
    float e = expf(v - m);
    red[q] = e; __syncthreads();
    for (int s = 64; s > 0; s >>= 1) { if (q < s) red[q] += red[q + s]; __syncthreads(); }
    float sum = red[0];
    p[row * 128 + q] = e / sum;
}

// ---------------- K4a: y = logits + 0.5*(p @ c_r)   (M=256, N=9472, K=128)
__global__ __launch_bounds__(256) void gemm_h_y(const float* __restrict__ pmat,
    const float* __restrict__ cache, const float* __restrict__ logits, float* __restrict__ y)
{
    __shared__ float As[128][68];
    __shared__ float Bs[128][68];
    int tid = threadIdx.x;
    int tx = tid & 15, ty = tid >> 4;
    int mt = blockIdx.x / 148, nt = blockIdx.x - mt * 148;
    int r0 = mt * 64, n0 = nt * 64;
    #pragma unroll
    for (int it = 0; it < 32; ++it) {
        int lin = it * 256 + tid;
        int r = lin >> 7, kk = lin & 127;
        As[kk][r] = pmat[(r0 + r) * 128 + kk];
    }
    #pragma unroll
    for (int it = 0; it < 32; ++it) {
        int lin = it * 256 + tid;
        int kk = lin >> 6, c = lin & 63;
        Bs[kk][c] = cache[kk * TK_ + n0 + c];
    }
    __syncthreads();
    float acc[4][4] = {};
    for (int kk = 0; kk < 128; ++kk) {
        float4 a = *(const float4*)&As[kk][4 * tx];
        float4 b = *(const float4*)&Bs[kk][4 * ty];
        const float* ap = (const float*)&a;
        const float* bp = (const float*)&b;
        #pragma unroll
        for (int i = 0; i < 4; ++i)
            #pragma unroll
            for (int j = 0; j < 4; ++j) acc[i][j] += ap[i] * bp[j];
    }
    #pragma unroll
    for (int i = 0; i < 4; ++i) {
        int r = r0 + 4 * tx + i;
        #pragma unroll
        for (int j = 0; j < 4; ++j) {
            int n = n0 + 4 * ty + j;
            y[r * TK_ + n] = logits[r * TK_ + n] + 0.5f * acc[i][j];
        }
    }
}

// ---------------- K4b: em = (y @ W2 + b2), transposed write. SGPR weights, no LDS.
__global__ __launch_bounds__(256) void gemm_em(const float* __restrict__ y,
    const float* __restrict__ W2q, const float* __restrict__ b2, float* __restrict__ em)
{
    int orig = blockIdx.x;                  // grid 512
    int vb = (orig & 7) * 64 + (orig >> 3);
    int rb = vb >> 2, nq = vb & 3;
    int tid = threadIdx.x;
    int r = rb * 256 + tid;
    int c0 = nq * 19;
    const float* wq = W2q + nq * (74 * 20);
    const float* yrow = y + (size_t)r * 74;
    float acc[20];
    #pragma unroll
    for (int j = 0; j < 20; ++j) acc[j] = 0.f;
    #pragma unroll 1
    for (int k0 = 0; k0 < 74; k0 += 2) {
        float2 a = *(const float2*)(yrow + k0);
        const float* ap = (const float*)&a;
        #pragma unroll
        for (int u = 0; u < 2; ++u) {
            const float* wr = wq + (k0 + u) * 20;
            #pragma unroll
            for (int j = 0; j < 20; ++j) acc[j] += ap[u] * wr[j];
        }
    }
    int b = r >> 7, t = r & 127;
    #pragma unroll
    for (int j = 0; j < 19; ++j) {
        int c = c0 + j;
        if (c < 74) em[t * EMS_ + b * 74 + c] = acc[j] + b2[c];
    }
}

// ---------------- K5: fused CRF scans. blocks 0..255 Viterbi(+backtrace), 256..511 normalizer.
__global__ __launch_bounds__(256) void crf_scan(const float* __restrict__ em,
    const int* __restrict__ mask_, const float* __restrict__ startv,
    const float* __restrict__ endv, const float* __restrict__ trans,
    float* __restrict__ out_tags, float* __restrict__ den)
{
    __shared__ float transS[74 * 74];
    __shared__ float scoreS[2][80];
    __shared__ float pv[3][74];
    __shared__ int   pi[3][74];
    __shared__ unsigned char histS[127 * 74];
    __shared__ float Ms[2];
    int tid = threadIdx.x;
    bool isV = blockIdx.x < 256;
    int b = isV ? blockIdx.x : (blockIdx.x - 256);

    for (int i = tid; i < 74 * 74; i += 256) transS[i] = trans[i];
    if (tid >= 74 && tid < 80) { scoreS[0][tid] = 0.f; scoreS[1][tid] = 0.f; }
    if (tid < 74) scoreS[0][tid] = startv[tid] + em[b * 74 + tid];
    __syncthreads();

    int ch = tid / 74;                 // 0..2 active (tid<222), 3 = idle
    int kp = tid - ch * 74;
    int cbase = (ch == 0) ? 0 : (ch == 1 ? 25 : 50);
    int cend  = (ch == 0) ? 25 : (ch == 1 ? 50 : 74);
    float tr[25];
    if (tid < 222) {
        #pragma unroll
        for (int j = 0; j < 25; ++j) {
            int kk = cbase + j;
            tr[j] = (kk < cend) ? transS[kk * 74 + kp] : -1.0e30f;
        }
    }
    int cur = 0;

    if (isV) {
        for (int t = 1; t < 128; ++t) {
            float e = (tid < 74) ? em[t * EMS_ + b * 74 + tid] : 0.f;
            if (tid < 222) {
                float m = -3.0e38f; int mi = cbase;
                #pragma unroll
                for (int j = 0; j < 25; ++j) {
                    float v = scoreS[cur][cbase + j] + tr[j];
                    if (v > m) { m = v; mi = cbase + j; }
                }
                pv[ch][kp] = m; pi[ch][kp] = mi;
            }
            __syncthreads();
            if (tid < 74) {
                float m0 = pv[0][tid]; int i0 = pi[0][tid];
                if (pv[1][tid] > m0) { m0 = pv[1][tid]; i0 = pi[1][tid]; }
                if (pv[2][tid] > m0) { m0 = pv[2][tid]; i0 = pi[2][tid]; }
                histS[(t - 1) * 74 + tid] = (unsigned char)i0;
                int mk = mask_[b * 128 + t];
                scoreS[cur ^ 1][tid] = mk ? (m0 + e) : scoreS[cur][tid];
            }
            __syncthreads();
            cur ^= 1;
        }
        if (tid == 0) {
            float bm = scoreS[cur][0] + endv[0]; int bi = 0;
            for (int k = 1; k < 74; ++k) {
                float v = scoreS[cur][k] + endv[k];
                if (v > bm) { bm = v; bi = k; }
            }
            int curk = bi;
            out_tags[b * 128 + 127] = (float)bi;
            for (int ti = 126; ti >= 0; --ti) {
                int mk = mask_[b * 128 + ti + 1];
                curk = mk ? (int)histS[ti * 74 + curk] : bi;
                out_tags[b * 128 + ti] = (float)curk;
            }
        }
    } else {
        float v0 = (tid < 74) ? scoreS[0][tid] : -3.0e38f;
        float M;
        if (tid < 128) {
            #pragma unroll
            for (int off = 32; off > 0; off >>= 1) v0 = fmaxf(v0, __shfl_xor(v0, off));
            if ((tid & 63) == 0) Ms[tid >> 6] = v0;
        }
        __syncthreads();
        M = fmaxf(Ms[0], Ms[1]);
        for (int t = 1; t < 128; ++t) {
            float e = (tid < 74) ? em[t * EMS_ + b * 74 + tid] : 0.f;
            if (tid < 222) {
                float s = 0.f;
                #pragma unroll
                for (int j = 0; j < 25; ++j)
                    s += __expf(scoreS[cur][cbase + j] + tr[j] - M);
                pv[ch][kp] = s;
            }
            __syncthreads();
            if (tid < 74) {
                float sum = pv[0][tid] + pv[1][tid] + pv[2][tid];
                float nxt = M + logf(sum) + e;
                int mk = mask_[b * 128 + t];
                scoreS[cur ^ 1][tid] = mk ? nxt : scoreS[cur][tid];
            }
            __syncthreads();
            cur ^= 1;
            float v = (tid < 74) ? scoreS[cur][tid] : -3.0e38f;
            if (tid < 128) {
                #pragma unroll
                for (int off = 32; off > 0; off >>= 1) v = fmaxf(v, __shfl_xor(v, off));
                if ((tid & 63) == 0) Ms[tid >> 6] = v;
            }
            __syncthreads();
            M = fmaxf(Ms[0], Ms[1]);
        }
        if (tid == 0) {
            float m = -3.0e38f;
            for (int k = 0; k < 74; ++k) m = fmaxf(m, scoreS[cur][k] + endv[k]);
            float s = 0.f;
            for (int k = 0; k < 74; ++k) s += __expf(scoreS[cur][k] + endv[k] - m);
            den[b] = m + logf(s);
        }
    }
}

// ---------------- K6: CRF score per batch (parallel over t), then final reduce
__global__ __launch_bounds__(128) void loss_partial(const float* __restrict__ em,
    const int* __restrict__ labels, const int* __restrict__ mask_,
    const float* __restrict__ startv, const float* __restrict__ endv,
    const float* __restrict__ den, const float* __restrict__ trans, float* __restrict__ nd)
{
    __shared__ float cs[2];
    __shared__ int ms[2];
    int b = blockIdx.x, t = threadIdx.x;
    int lab = labels[b * 128 + t];
    int mk = mask_[b * 128 + t];
    float contrib;
    if (t == 0) {
        contrib = startv[lab] + em[b * 74 + lab];
    } else {
        int labp = labels[b * 128 + t - 1];
        contrib = mk ? (trans[labp * 74 + lab] + em[t * EMS_ + b * 74 + lab]) : 0.f;
    }
    float c = contrib; int m = mk;
    #pragma unroll
    for (int off = 32; off > 0; off >>= 1) {
        c += __shfl_xor(c, off);
        m += __shfl_xor(m, off);
    }
    if ((t & 63) == 0) { cs[t >> 6] = c; ms[t >> 6] = m; }
    __syncthreads();
    if (t == 0) {
        float num = cs[0] + cs[1];
        int msum = ms[0] + ms[1];
        int last = labels[b * 128 + msum - 1];
        num += endv[last];
        nd[b] = num - den[b];
    }
}

__global__ void loss_final(const float* __restrict__ nd, float* __restrict__ out_loss)
{
    __shared__ float red[256];
    int i = threadIdx.x;
    red[i] = nd[i];
    __syncthreads();
    for (int s = 128; s > 0; s >>= 1) { if (i < s) red[i] += red[i + s]; __syncthreads(); }
    if (i == 0) out_loss[0] = -(red[0] / 256.f);
}

extern "C" void kernel_launch(void* const* d_in, const int* in_sizes, int n_in,
                              void* d_out, int out_size, void* d_ws, size_t ws_size,
                              hipStream_t stream)
{
    const float* feats  = (const float*)d_in[0];
    const int*   amask  = (const int*)d_in[1];
    const int*   labels = (const int*)d_in[2];
    const float* cache  = (const float*)d_in[3];
    const float* W1     = (const float*)d_in[4];
    const float* b1     = (const float*)d_in[5];
    const float* W2     = (const float*)d_in[6];
    const float* b2     = (const float*)d_in[7];
    const float* startv = (const float*)d_in[8];
    const float* endv   = (const float*)d_in[9];
    const float* trans  = (const float*)d_in[10];

    float* ws     = (float*)d_ws;
    float* logits = ws;                 // 2,424,832
    float* y      = ws + 2424832;       // 2,424,832
    float* em     = ws + 4849664;       // 2,424,832
    float* part   = ws + 7274496;       // 1,048,576
    float* sim    = ws + 8323072;       // 32,768
    float* p      = ws + 8355840;       // 32,768
    float* den    = ws + 8388608;       // 256
    float* nd     = ws + 8388864;       // 256
    float* W1q    = ws + 8389120;       // 61,440
    float* W2q    = ws + 8450560;       // 5,920
    float* out_tags = (float*)d_out;
    float* out_loss = (float*)d_out + 32768;

    hipLaunchKernelGGL(pad_weights,  dim3(240), dim3(256), 0, stream, W1, W2, W1q, W2q);
    hipLaunchKernelGGL(gemm_logits,  dim3(512), dim3(256), 0, stream, feats, W1q, b1, logits);
    hipLaunchKernelGGL(sim_partial,  dim3(256), dim3(256), 0, stream, logits, cache, part);
    hipLaunchKernelGGL(sim_reduce,   dim3(128), dim3(256), 0, stream, part, sim);
    hipLaunchKernelGGL(softmax128,   dim3(256), dim3(128), 0, stream, sim, p);
    hipLaunchKernelGGL(gemm_h_y,     dim3(592), dim3(256), 0, stream, p, cache, logits, y);
    hipLaunchKernelGGL(gemm_em,      dim3(512), dim3(256), 0, stream, y, W2q, b2, em);
    hipLaunchKernelGGL(crf_scan,     dim3(512), dim3(256), 0, stream, em, amask, startv, endv, trans, out_tags, den);
    hipLaunchKernelGGL(loss_partial, dim3(256), dim3(128), 0, stream, em, labels, amask, startv, endv, den, trans, nd);
    hipLaunchKernelGGL(loss_final,   dim3(1),   dim3(256), 0, stream, nd, out_loss);
}

// Round 4
// 335.133 us; speedup vs baseline: 1.5199x; 1.0220x over previous
//
#include <hip/hip_runtime.h>

#define B_ 256
#define T_ 128
#define D_ 768
#define K_ 74
#define C_ 128
#define TK_ 9472      // T_*K_
#define BT_ 32768     // B_*T_
#define EMS_ 18944    // B_*K_  (em time-slice stride)

#define LGKM_BARRIER() do { \
    asm volatile("s_waitcnt lgkmcnt(0)" ::: "memory"); \
    __builtin_amdgcn_s_barrier(); \
    __builtin_amdgcn_sched_barrier(0); \
} while (0)

// ---------------- K0: pad W1 -> W1q[4][768][20], W2 -> W2q[4][74][20]
__global__ void pad_weights(const float* __restrict__ W1, const float* __restrict__ W2,
                            float* __restrict__ W1q, float* __restrict__ W2q)
{
    int idx = blockIdx.x * 256 + threadIdx.x;
    if (idx < 4 * 768 * 20) {
        int nq = idx / (768 * 20); int rem = idx - nq * (768 * 20);
        int k = rem / 20, j = rem - k * 20;
        int c = nq * 19 + j;
        W1q[idx] = (j < 19 && c < 74) ? W1[k * 74 + c] : 0.f;
    }
    if (idx < 4 * 74 * 20) {
        int nq = idx / (74 * 20); int rem = idx - nq * (74 * 20);
        int k = rem / 20, j = rem - k * 20;
        int c = nq * 19 + j;
        W2q[idx] = (j < 19 && c < 74) ? W2[k * 74 + c] : 0.f;
    }
}

// ---------------- K1: logits = feats @ W1 + b1  (M=32768, N=74, K=768)
__global__ __launch_bounds__(256) void gemm_logits(const float* __restrict__ feats,
    const float* __restrict__ W1q, const float* __restrict__ b1, float* __restrict__ logits)
{
    int orig = blockIdx.x;
    int vb = (orig & 7) * 64 + (orig >> 3);
    int rb = vb >> 2, nq = vb & 3;
    int tid = threadIdx.x;
    int r = rb * 256 + tid;
    int c0 = nq * 19;
    const float* frow = feats + (size_t)r * 768;
    const float* wq = W1q + nq * (768 * 20);
    float acc[20];
    #pragma unroll
    for (int j = 0; j < 20; ++j) acc[j] = 0.f;

    for (int k0 = 0; k0 < 768; k0 += 16) {
        float4 a[4];
        #pragma unroll
        for (int q = 0; q < 4; ++q) a[q] = *(const float4*)(frow + k0 + 4 * q);
        #pragma unroll
        for (int u = 0; u < 16; ++u) {
            float av = ((const float*)a)[u];
            const float* wr = wq + (k0 + u) * 20;
            #pragma unroll
            for (int j = 0; j < 20; ++j) acc[j] += av * wr[j];
        }
    }
    #pragma unroll
    for (int j = 0; j < 19; ++j) {
        int c = c0 + j;
        if (c < 74) logits[(size_t)r * 74 + c] = acc[j] + b1[c];
    }
}

// ---------------- K2: sim partials
__global__ __launch_bounds__(256) void sim_partial(const float* __restrict__ logits,
    const float* __restrict__ cache, float* __restrict__ part)
{
    __shared__ float As[74][68];
    __shared__ float Bs[74][68];
    int tid = threadIdx.x;
    int tx = tid & 15, ty = tid >> 4;
    int bid = blockIdx.x;
    int jc = bid >> 3;
    int mt = (bid >> 1) & 3;
    int nt = bid & 1;
    int p0 = mt * 64, q0 = nt * 64;
    float acc[4][4] = {};
    for (int jj = 0; jj < 4; ++jj) {
        int j = jc * 4 + jj;
        for (int it = 0; it < 19; ++it) {
            int lin = it * 256 + tid;
            if (lin < 64 * 74) {
                int r = lin / 74, ik = lin - r * 74;
                As[ik][r] = logits[(p0 + r) * TK_ + j * 74 + ik];
                Bs[ik][r] = cache[(q0 + r) * TK_ + j * 74 + ik];
            }
        }
        __syncthreads();
        for (int ik = 0; ik < 74; ++ik) {
            float4 a = *(const float4*)&As[ik][4 * tx];
            float4 b = *(const float4*)&Bs[ik][4 * ty];
            const float* ap = (const float*)&a;
            const float* bp = (const float*)&b;
            #pragma unroll
            for (int i = 0; i < 4; ++i)
                #pragma unroll
                for (int q = 0; q < 4; ++q) acc[i][q] += ap[i] * bp[q];
        }
        __syncthreads();
    }
    #pragma unroll
    for (int i = 0; i < 4; ++i)
        #pragma unroll
        for (int q = 0; q < 4; ++q)
            part[jc * (B_ * C_) + (p0 + 4 * tx + i) * C_ + q0 + 4 * ty + q] = acc[i][q];
}

__global__ void sim_reduce(const float* __restrict__ part, float* __restrict__ sim)
{
    int idx = blockIdx.x * 256 + threadIdx.x;
    float s = 0.f;
    for (int jc = 0; jc < 32; ++jc) s += part[jc * (B_ * C_) + idx];
    sim[idx] = s;
}

__global__ void softmax128(const float* __restrict__ sim, float* __restrict__ p)
{
    __shared__ float red[128];
    int q = threadIdx.x, row = blockIdx.x;
    float v = sim[row * 128 + q];
    red[q] = v; __syncthreads();
    for (int s = 64; s > 0; s >>= 1) { if (q < s) red[q] = fmaxf(red[q], red[q + s]); __syncthreads(); }
    float m = red[0]; __syncthreads();
    float e = expf(v - m);
    red[q] = e; __syncthreads();
    for (int s = 64; s > 0; s >>= 1) { if (q < s) red[q] += red[q + s]; __syncthreads(); }
    float sum = red[0];
    p[row * 128 + q] = e / sum;
}

// ---------------- K4a: y = logits + 0.5*(p @ c_r)
__global__ __launch_bounds__(256) void gemm_h_y(const float* __restrict__ pmat,
    const float* __restrict__ cache, const float* __restrict__ logits, float* __restrict__ y)
{
    __shared__ float As[128][68];
    __shared__ float Bs[128][68];
    int tid = threadIdx.x;
    int tx = tid & 15, ty = tid >> 4;
    int mt = blockIdx.x / 148, nt = blockIdx.x - mt * 148;
    int r0 = mt * 64, n0 = nt * 64;
    #pragma unroll
    for (int it = 0; it < 32; ++it) {
        int lin = it * 256 + tid;
        int r = lin >> 7, kk = lin & 127;
        As[kk][r] = pmat[(r0 + r) * 128 + kk];
    }
    #pragma unroll
    for (int it = 0; it < 32; ++it) {
        int lin = it * 256 + tid;
        int kk = lin >> 6, c = lin & 63;
        Bs[kk][c] = cache[kk * TK_ + n0 + c];
    }
    __syncthreads();
    float acc[4][4] = {};
    for (int kk = 0; kk < 128; ++kk) {
        float4 a = *(const float4*)&As[kk][4 * tx];
        float4 b = *(const float4*)&Bs[kk][4 * ty];
        const float* ap = (const float*)&a;
        const float* bp = (const float*)&b;
        #pragma unroll
        for (int i = 0; i < 4; ++i)
            #pragma unroll
            for (int j = 0; j < 4; ++j) acc[i][j] += ap[i] * bp[j];
    }
    #pragma unroll
    for (int i = 0; i < 4; ++i) {
        int r = r0 + 4 * tx + i;
        #pragma unroll
        for (int j = 0; j < 4; ++j) {
            int n = n0 + 4 * ty + j;
            y[r * TK_ + n] = logits[r * TK_ + n] + 0.5f * acc[i][j];
        }
    }
}

// ---------------- K4b: em = (y @ W2 + b2), transposed write
__global__ __launch_bounds__(256) void gemm_em(const float* __restrict__ y,
    const float* __restrict__ W2q, const float* __restrict__ b2, float* __restrict__ em)
{
    int orig = blockIdx.x;
    int vb = (orig & 7) * 64 + (orig >> 3);
    int rb = vb >> 2, nq = vb & 3;
    int tid = threadIdx.x;
    int r = rb * 256 + tid;
    int c0 = nq * 19;
    const float* wq = W2q + nq * (74 * 20);
    const float* yrow = y + (size_t)r * 74;
    float acc[20];
    #pragma unroll
    for (int j = 0; j < 20; ++j) acc[j] = 0.f;
    #pragma unroll 1
    for (int k0 = 0; k0 < 74; k0 += 2) {
        float2 a = *(const float2*)(yrow + k0);
        const float* ap = (const float*)&a;
        #pragma unroll
        for (int u = 0; u < 2; ++u) {
            const float* wr = wq + (k0 + u) * 20;
            #pragma unroll
            for (int j = 0; j < 20; ++j) acc[j] += ap[u] * wr[j];
        }
    }
    int b = r >> 7, t = r & 127;
    #pragma unroll
    for (int j = 0; j < 19; ++j) {
        int c = c0 + j;
        if (c < 74) em[t * EMS_ + b * 74 + c] = acc[j] + b2[c];
    }
}

// ---------------- K5: fused CRF scans, lgkm-only barriers in the scan loop.
__global__ __launch_bounds__(256) void crf_scan(const float* __restrict__ em,
    const int* __restrict__ mask_, const float* __restrict__ startv,
    const float* __restrict__ endv, const float* __restrict__ trans,
    float* __restrict__ out_tags, float* __restrict__ den)
{
    __shared__ float transS[74 * 74];
    __shared__ float scoreS[2][80];
    __shared__ float pv[3][74];
    __shared__ int   pi[3][74];
    __shared__ unsigned char histS[127 * 74];
    __shared__ float Ms[2];
    int tid = threadIdx.x;
    bool isV = blockIdx.x < 256;
    int b = isV ? blockIdx.x : (blockIdx.x - 256);

    for (int i = tid; i < 74 * 74; i += 256) transS[i] = trans[i];
    if (tid < 74) scoreS[0][tid] = startv[tid] + em[b * 74 + tid];
    __syncthreads();

    int ch = tid / 74;                 // 0..2 active (tid<222)
    int kp = tid - ch * 74;
    int cbase = (ch == 0) ? 0 : (ch == 1 ? 25 : 50);
    int cend  = (ch == 0) ? 25 : (ch == 1 ? 50 : 74);
    float tr[25];
    if (tid < 222) {
        #pragma unroll
        for (int j = 0; j < 25; ++j) {
            int kk = cbase + j;
            tr[j] = (kk < cend) ? transS[kk * 74 + kp] : -1.0e30f;
        }
    }
    int cur = 0;

    if (isV) {
        for (int t = 1; t < 128; ++t) {
            float e = (tid < 74) ? em[t * EMS_ + b * 74 + tid] : 0.f;  // stays in flight
            int mk = mask_[b * 128 + t];
            if (tid < 222) {
                float m = -3.0e38f; int mi = cbase;
                #pragma unroll
                for (int j = 0; j < 25; ++j) {
                    float v = scoreS[cur][cbase + j] + tr[j];
                    if (v > m) { m = v; mi = cbase + j; }
                }
                pv[ch][kp] = m; pi[ch][kp] = mi;
            }
            LGKM_BARRIER();
            if (tid < 74) {
                float m0 = pv[0][tid]; int i0 = pi[0][tid];
                if (pv[1][tid] > m0) { m0 = pv[1][tid]; i0 = pi[1][tid]; }
                if (pv[2][tid] > m0) { m0 = pv[2][tid]; i0 = pi[2][tid]; }
                histS[(t - 1) * 74 + tid] = (unsigned char)i0;
                scoreS[cur ^ 1][tid] = mk ? (m0 + e) : scoreS[cur][tid];
            }
            LGKM_BARRIER();
            cur ^= 1;
        }
        if (tid == 0) {
            float bm = scoreS[cur][0] + endv[0]; int bi = 0;
            for (int k = 1; k < 74; ++k) {
                float v = scoreS[cur][k] + endv[k];
                if (v > bm) { bm = v; bi = k; }
            }
            int curk = bi;
            out_tags[b * 128 + 127] = (float)bi;
            for (int ti = 126; ti >= 0; --ti) {
                int mk = mask_[b * 128 + ti + 1];
                curk = mk ? (int)histS[ti * 74 + curk] : bi;
                out_tags[b * 128 + ti] = (float)curk;
            }
        }
    } else {
        // initial running max M over score0
        float v0 = (tid < 74) ? scoreS[0][tid] : -3.0e38f;
        float M;
        if (tid < 128) {
            #pragma unroll
            for (int off = 32; off > 0; off >>= 1) v0 = fmaxf(v0, __shfl_xor(v0, off));
            if ((tid & 63) == 0) Ms[tid >> 6] = v0;
        }
        __syncthreads();
        M = fmaxf(Ms[0], Ms[1]);
        for (int t = 1; t < 128; ++t) {
            float e = (tid < 74) ? em[t * EMS_ + b * 74 + tid] : 0.f;
            int mk = mask_[b * 128 + t];
            if (tid < 222) {
                float s0 = 0.f, s1 = 0.f;
                #pragma unroll
                for (int j = 0; j < 25; j += 2) {
                    s0 += __expf(scoreS[cur][cbase + j] + tr[j] - M);
                    if (j + 1 < 25) s1 += __expf(scoreS[cur][cbase + j + 1] + tr[j + 1] - M);
                }
                pv[ch][kp] = s0 + s1;
            }
            LGKM_BARRIER();
            float vred = -3.0e38f;
            if (tid < 74) {
                float sum = pv[0][tid] + pv[1][tid] + pv[2][tid];
                float nxt = M + __logf(sum) + e;
                float snew = mk ? nxt : scoreS[cur][tid];
                scoreS[cur ^ 1][tid] = snew;
                vred = snew;
            }
            if (tid < 128) {   // fold next-M reduce into this phase (regs, no LDS re-read)
                #pragma unroll
                for (int off = 32; off > 0; off >>= 1) vred = fmaxf(vred, __shfl_xor(vred, off));
                if ((tid & 63) == 0) Ms[tid >> 6] = vred;
            }
            LGKM_BARRIER();
            M = fmaxf(Ms[0], Ms[1]);
            cur ^= 1;
        }
        if (tid == 0) {
            float m = -3.0e38f;
            for (int k = 0; k < 74; ++k) m = fmaxf(m, scoreS[cur][k] + endv[k]);
            float s = 0.f;
            for (int k = 0; k < 74; ++k) s += __expf(scoreS[cur][k] + endv[k] - m);
            den[b] = m + __logf(s);
        }
    }
}

// ---------------- K6: CRF score per batch, then final reduce
__global__ __launch_bounds__(128) void loss_partial(const float* __restrict__ em,
    const int* __restrict__ labels, const int* __restrict__ mask_,
    const float* __restrict__ startv, const float* __restrict__ endv,
    const float* __restrict__ den, const float* __restrict__ trans, float* __restrict__ nd)
{
    __shared__ float cs[2];
    __shared__ int ms[2];
    int b = blockIdx.x, t = threadIdx.x;
    int lab = labels[b * 128 + t];
    int mk = mask_[b * 128 + t];
    float contrib;
    if (t == 0) {
        contrib = startv[lab] + em[b * 74 + lab];
    } else {
        int labp = labels[b * 128 + t - 1];
        contrib = mk ? (trans[labp * 74 + lab] + em[t * EMS_ + b * 74 + lab]) : 0.f;
    }
    float c = contrib; int m = mk;
    #pragma unroll
    for (int off = 32; off > 0; off >>= 1) {
        c += __shfl_xor(c, off);
        m += __shfl_xor(m, off);
    }
    if ((t & 63) == 0) { cs[t >> 6] = c; ms[t >> 6] = m; }
    __syncthreads();
    if (t == 0) {
        float num = cs[0] + cs[1];
        int msum = ms[0] + ms[1];
        int last = labels[b * 128 + msum - 1];
        num += endv[last];
        nd[b] = num - den[b];
    }
}

__global__ void loss_final(const float* __restrict__ nd, float* __restrict__ out_loss)
{
    __shared__ float red[256];
    int i = threadIdx.x;
    red[i] = nd[i];
    __syncthreads();
    for (int s = 128; s > 0; s >>= 1) { if (i < s) red[i] += red[i + s]; __syncthreads(); }
    if (i == 0) out_loss[0] = -(red[0] / 256.f);
}

extern "C" void kernel_launch(void* const* d_in, const int* in_sizes, int n_in,
                              void* d_out, int out_size, void* d_ws, size_t ws_size,
                              hipStream_t stream)
{
    const float* feats  = (const float*)d_in[0];
    const int*   amask  = (const int*)d_in[1];
    const int*   labels = (const int*)d_in[2];
    const float* cache  = (const float*)d_in[3];
    const float* W1     = (const float*)d_in[4];
    const float* b1     = (const float*)d_in[5];
    const float* W2     = (const float*)d_in[6];
    const float* b2     = (const float*)d_in[7];
    const float* startv = (const float*)d_in[8];
    const float* endv   = (const float*)d_in[9];
    const float* trans  = (const float*)d_in[10];

    float* ws     = (float*)d_ws;
    float* logits = ws;                 // 2,424,832
    float* y      = ws + 2424832;       // 2,424,832
    float* em     = ws + 4849664;       // 2,424,832
    float* part   = ws + 7274496;       // 1,048,576
    float* sim    = ws + 8323072;       // 32,768
    float* p      = ws + 8355840;       // 32,768
    float* den    = ws + 8388608;       // 256
    float* nd     = ws + 8388864;       // 256
    float* W1q    = ws + 8389120;       // 61,440
    float* W2q    = ws + 8450560;       // 5,920
    float* out_tags = (float*)d_out;
    float* out_loss = (float*)d_out + 32768;

    hipLaunchKernelGGL(pad_weights,  dim3(240), dim3(256), 0, stream, W1, W2, W1q, W2q);
    hipLaunchKernelGGL(gemm_logits,  dim3(512), dim3(256), 0, stream, feats, W1q, b1, logits);
    hipLaunchKernelGGL(sim_partial,  dim3(256), dim3(256), 0, stream, logits, cache, part);
    hipLaunchKernelGGL(sim_reduce,   dim3(128), dim3(256), 0, stream, part, sim);
    hipLaunchKernelGGL(softmax128,   dim3(256), dim3(128), 0, stream, sim, p);
    hipLaunchKernelGGL(gemm_h_y,     dim3(592), dim3(256), 0, stream, p, cache, logits, y);
    hipLaunchKernelGGL(gemm_em,      dim3(512), dim3(256), 0, stream, y, W2q, b2, em);
    hipLaunchKernelGGL(crf_scan,     dim3(512), dim3(256), 0, stream, em, amask, startv, endv, trans, out_tags, den);
    hipLaunchKernelGGL(loss_partial, dim3(256), dim3(128), 0, stream, em, labels, amask, startv, endv, den, trans, nd);
    hipLaunchKernelGGL(loss_final,   dim3(1),   dim3(256), 0, stream, nd, out_loss);
}

// Round 5
// 317.504 us; speedup vs baseline: 1.6043x; 1.0555x over previous
//
#include <hip/hip_runtime.h>

#define B_ 256
#define T_ 128
#define D_ 768
#define K_ 74
#define C_ 128
#define TK_ 9472      // T_*K_
#define BT_ 32768     // B_*T_
#define EMS_ 18944    // B_*K_  (em time-slice stride)

#define LGKM_BARRIER() do { \
    asm volatile("s_waitcnt lgkmcnt(0)" ::: "memory"); \
    __builtin_amdgcn_s_barrier(); \
    __builtin_amdgcn_sched_barrier(0); \
} while (0)

// ---------------- K0: pad W1 -> W1q[4][768][20], W2 -> W2q[4][74][20]
__global__ void pad_weights(const float* __restrict__ W1, const float* __restrict__ W2,
                            float* __restrict__ W1q, float* __restrict__ W2q)
{
    int idx = blockIdx.x * 256 + threadIdx.x;
    if (idx < 4 * 768 * 20) {
        int nq = idx / (768 * 20); int rem = idx - nq * (768 * 20);
        int k = rem / 20, j = rem - k * 20;
        int c = nq * 19 + j;
        W1q[idx] = (j < 19 && c < 74) ? W1[k * 74 + c] : 0.f;
    }
    if (idx < 4 * 74 * 20) {
        int nq = idx / (74 * 20); int rem = idx - nq * (74 * 20);
        int k = rem / 20, j = rem - k * 20;
        int c = nq * 19 + j;
        W2q[idx] = (j < 19 && c < 74) ? W2[k * 74 + c] : 0.f;
    }
}

// ---------------- K1: logits = feats @ W1 + b1  (M=32768, N=74, K=768)
__global__ __launch_bounds__(256) void gemm_logits(const float* __restrict__ feats,
    const float* __restrict__ W1q, const float* __restrict__ b1, float* __restrict__ logits)
{
    int orig = blockIdx.x;
    int vb = (orig & 7) * 64 + (orig >> 3);
    int rb = vb >> 2, nq = vb & 3;
    int tid = threadIdx.x;
    int r = rb * 256 + tid;
    int c0 = nq * 19;
    const float* frow = feats + (size_t)r * 768;
    const float* wq = W1q + nq * (768 * 20);
    float acc[20];
    #pragma unroll
    for (int j = 0; j < 20; ++j) acc[j] = 0.f;

    for (int k0 = 0; k0 < 768; k0 += 16) {
        float4 a[4];
        #pragma unroll
        for (int q = 0; q < 4; ++q) a[q] = *(const float4*)(frow + k0 + 4 * q);
        #pragma unroll
        for (int u = 0; u < 16; ++u) {
            float av = ((const float*)a)[u];
            const float* wr = wq + (k0 + u) * 20;
            #pragma unroll
            for (int j = 0; j < 20; ++j) acc[j] += av * wr[j];
        }
    }
    #pragma unroll
    for (int j = 0; j < 19; ++j) {
        int c = c0 + j;
        if (c < 74) logits[(size_t)r * 74 + c] = acc[j] + b1[c];
    }
}

// ---------------- K2: sim partials
__global__ __launch_bounds__(256) void sim_partial(const float* __restrict__ logits,
    const float* __restrict__ cache, float* __restrict__ part)
{
    __shared__ float As[74][68];
    __shared__ float Bs[74][68];
    int tid = threadIdx.x;
    int tx = tid & 15, ty = tid >> 4;
    int bid = blockIdx.x;
    int jc = bid >> 3;
    int mt = (bid >> 1) & 3;
    int nt = bid & 1;
    int p0 = mt * 64, q0 = nt * 64;
    float acc[4][4] = {};
    for (int jj = 0; jj < 4; ++jj) {
        int j = jc * 4 + jj;
        for (int it = 0; it < 19; ++it) {
            int lin = it * 256 + tid;
            if (lin < 64 * 74) {
                int r = lin / 74, ik = lin - r * 74;
                As[ik][r] = logits[(p0 + r) * TK_ + j * 74 + ik];
                Bs[ik][r] = cache[(q0 + r) * TK_ + j * 74 + ik];
            }
        }
        __syncthreads();
        for (int ik = 0; ik < 74; ++ik) {
            float4 a = *(const float4*)&As[ik][4 * tx];
            float4 b = *(const float4*)&Bs[ik][4 * ty];
            const float* ap = (const float*)&a;
            const float* bp = (const float*)&b;
            #pragma unroll
            for (int i = 0; i < 4; ++i)
                #pragma unroll
                for (int q = 0; q < 4; ++q) acc[i][q] += ap[i] * bp[q];
        }
        __syncthreads();
    }
    #pragma unroll
    for (int i = 0; i < 4; ++i)
        #pragma unroll
        for (int q = 0; q < 4; ++q)
            part[jc * (B_ * C_) + (p0 + 4 * tx + i) * C_ + q0 + 4 * ty + q] = acc[i][q];
}

__global__ void sim_reduce(const float* __restrict__ part, float* __restrict__ sim)
{
    int idx = blockIdx.x * 256 + threadIdx.x;
    float s = 0.f;
    for (int jc = 0; jc < 32; ++jc) s += part[jc * (B_ * C_) + idx];
    sim[idx] = s;
}

__global__ void softmax128(const float* __restrict__ sim, float* __restrict__ p)
{
    __shared__ float red[128];
    int q = threadIdx.x, row = blockIdx.x;
    float v = sim[row * 128 + q];
    red[q] = v; __syncthreads();
    for (int s = 64; s > 0; s >>= 1) { if (q < s) red[q] = fmaxf(red[q], red[q + s]); __syncthreads(); }
    float m = red[0]; __syncthreads();
    float e = expf(v - m);
    red[q] = e; __syncthreads();
    for (int s = 64; s > 0; s >>= 1) { if (q < s) red[q] += red[q + s]; __syncthreads(); }
    float sum = red[0];
    p[row * 128 + q] = e / sum;
}

// ---------------- K4a: y = logits + 0.5*(p @ c_r)
__global__ __launch_bounds__(256) void gemm_h_y(const float* __restrict__ pmat,
    const float* __restrict__ cache, const float* __restrict__ logits, float* __restrict__ y)
{
    __shared__ float As[128][68];
    __shared__ float Bs[128][68];
    int tid = threadIdx.x;
    int tx = tid & 15, ty = tid >> 4;
    int mt = blockIdx.x / 148, nt = blockIdx.x - mt * 148;
    int r0 = mt * 64, n0 = nt * 64;
    #pragma unroll
    for (int it = 0; it < 32; ++it) {
        int lin = it * 256 + tid;
        int r = lin >> 7, kk = lin & 127;
        As[kk][r] = pmat[(r0 + r) * 128 + kk];
    }
    #pragma unroll
    for (int it = 0; it < 32; ++it) {
        int lin = it * 256 + tid;
        int kk = lin >> 6, c = lin & 63;
        Bs[kk][c] = cache[kk * TK_ + n0 + c];
    }
    __syncthreads();
    float acc[4][4] = {};
    for (int kk = 0; kk < 128; ++kk) {
        float4 a = *(const float4*)&As[kk][4 * tx];
        float4 b = *(const float4*)&Bs[kk][4 * ty];
        const float* ap = (const float*)&a;
        const float* bp = (const float*)&b;
        #pragma unroll
        for (int i = 0; i < 4; ++i)
            #pragma unroll
            for (int j = 0; j < 4; ++j) acc[i][j] += ap[i] * bp[j];
    }
    #pragma unroll
    for (int i = 0; i < 4; ++i) {
        int r = r0 + 4 * tx + i;
        #pragma unroll
        for (int j = 0; j < 4; ++j) {
            int n = n0 + 4 * ty + j;
            y[r * TK_ + n] = logits[r * TK_ + n] + 0.5f * acc[i][j];
        }
    }
}

// ---------------- K4b: em = (y @ W2 + b2), transposed write
__global__ __launch_bounds__(256) void gemm_em(const float* __restrict__ y,
    const float* __restrict__ W2q, const float* __restrict__ b2, float* __restrict__ em)
{
    int orig = blockIdx.x;
    int vb = (orig & 7) * 64 + (orig >> 3);
    int rb = vb >> 2, nq = vb & 3;
    int tid = threadIdx.x;
    int r = rb * 256 + tid;
    int c0 = nq * 19;
    const float* wq = W2q + nq * (74 * 20);
    const float* yrow = y + (size_t)r * 74;
    float acc[20];
    #pragma unroll
    for (int j = 0; j < 20; ++j) acc[j] = 0.f;
    #pragma unroll 1
    for (int k0 = 0; k0 < 74; k0 += 2) {
        float2 a = *(const float2*)(yrow + k0);
        const float* ap = (const float*)&a;
        #pragma unroll
        for (int u = 0; u < 2; ++u) {
            const float* wr = wq + (k0 + u) * 20;
            #pragma unroll
            for (int j = 0; j < 20; ++j) acc[j] += ap[u] * wr[j];
        }
    }
    int b = r >> 7, t = r & 127;
    #pragma unroll
    for (int j = 0; j < 19; ++j) {
        int c = c0 + j;
        if (c < 74) em[t * EMS_ + b * 74 + c] = acc[j] + b2[c];
    }
}

// ---------------- K5: fused CRF scans. em prefetch depth-2, defer-max normalizer,
// mask staged in LDS, b128 broadcast score reads (chunks of 28).
__global__ __launch_bounds__(256) void crf_scan(const float* __restrict__ em,
    const int* __restrict__ mask_, const float* __restrict__ startv,
    const float* __restrict__ endv, const float* __restrict__ trans,
    float* __restrict__ out_tags, float* __restrict__ den)
{
    __shared__ float transS[74 * 74];
    __shared__ float scoreS[2][88];
    __shared__ float pv[3][74];
    __shared__ int   pi[3][74];
    __shared__ unsigned char histS[127 * 74];
    __shared__ float tagsS[128];
    __shared__ float Ms[2];
    __shared__ int   flagU[2];
    __shared__ int   maskS[128];
    int tid = threadIdx.x;
    bool isV = blockIdx.x < 256;
    int b = isV ? blockIdx.x : (blockIdx.x - 256);

    for (int i = tid; i < 74 * 74; i += 256) transS[i] = trans[i];
    if (tid < 128) maskS[tid] = mask_[b * 128 + tid];
    if (tid >= 74 && tid < 88) { scoreS[0][tid] = -3.0e38f; scoreS[1][tid] = -3.0e38f; }
    if (tid < 74) scoreS[0][tid] = startv[tid] + em[b * 74 + tid];
    __syncthreads();

    int ch = (tid < 74) ? 0 : (tid < 148 ? 1 : 2);   // 3 chunks of 28 sources
    int kp = tid - ch * 74;                          // dest state
    int cbase = ch * 28;
    float tr[28];
    if (tid < 222) {
        #pragma unroll
        for (int j = 0; j < 28; ++j) {
            int kk = cbase + j;
            tr[j] = (kk < 74) ? transS[kk * 74 + kp] : -1.0e30f;
        }
    }
    int cur = 0;

    // depth-2 em prefetch registers
    float eA = 0.f, eB = 0.f;
    if (tid < 74) {
        eA = em[1 * EMS_ + b * 74 + tid];
        eB = em[2 * EMS_ + b * 74 + tid];
    }

    if (isV) {
        for (int t = 1; t < 128; ++t) {
            float eC = 0.f;
            if (tid < 74 && t + 2 < 128) eC = em[(t + 2) * EMS_ + b * 74 + tid];
            if (tid < 222) {
                float m = -3.0e38f; int mi = cbase;
                #pragma unroll
                for (int jj = 0; jj < 7; ++jj) {
                    float4 s4 = *(const float4*)&scoreS[cur][cbase + 4 * jj];
                    const float* sp = (const float*)&s4;
                    #pragma unroll
                    for (int u = 0; u < 4; ++u) {
                        float v = sp[u] + tr[4 * jj + u];
                        if (v > m) { m = v; mi = cbase + 4 * jj + u; }
                    }
                }
                pv[ch][kp] = m; pi[ch][kp] = mi;
            }
            LGKM_BARRIER();
            int mk = maskS[t];
            if (tid < 74) {
                float m0 = pv[0][tid]; int i0 = pi[0][tid];
                if (pv[1][tid] > m0) { m0 = pv[1][tid]; i0 = pi[1][tid]; }
                if (pv[2][tid] > m0) { m0 = pv[2][tid]; i0 = pi[2][tid]; }
                histS[(t - 1) * 74 + tid] = (unsigned char)i0;
                scoreS[cur ^ 1][tid] = mk ? (m0 + eA) : scoreS[cur][tid];
            }
            LGKM_BARRIER();
            cur ^= 1;
            eA = eB; eB = eC;
        }
        if (tid == 0) {
            float bm = scoreS[cur][0] + endv[0]; int bi = 0;
            for (int k = 1; k < 74; ++k) {
                float v = scoreS[cur][k] + endv[k];
                if (v > bm) { bm = v; bi = k; }
            }
            int curk = bi;
            tagsS[127] = (float)bi;
            for (int ti = 126; ti >= 0; --ti) {
                int mk = maskS[ti + 1];
                curk = mk ? (int)histS[ti * 74 + curk] : bi;
                tagsS[ti] = (float)curk;
            }
        }
        __syncthreads();
        if (tid < 128) out_tags[b * 128 + tid] = tagsS[tid];
    } else {
        // exact initial stabilizer M
        float v0 = (tid < 74) ? scoreS[0][tid] : -3.0e38f;
        float M;
        if (tid < 128) {
            #pragma unroll
            for (int off = 32; off > 0; off >>= 1) v0 = fmaxf(v0, __shfl_xor(v0, off));
            if ((tid & 63) == 0) Ms[tid >> 6] = v0;
        }
        __syncthreads();
        M = fmaxf(Ms[0], Ms[1]);
        for (int t = 1; t < 128; ++t) {
            float eC = 0.f;
            if (tid < 74 && t + 2 < 128) eC = em[(t + 2) * EMS_ + b * 74 + tid];
            if (tid < 222) {
                float s0 = 0.f, s1 = 0.f, s2 = 0.f, s3 = 0.f;
                #pragma unroll
                for (int jj = 0; jj < 7; ++jj) {
                    float4 s4 = *(const float4*)&scoreS[cur][cbase + 4 * jj];
                    const float* sp = (const float*)&s4;
                    s0 += __expf(sp[0] + tr[4 * jj + 0] - M);
                    s1 += __expf(sp[1] + tr[4 * jj + 1] - M);
                    s2 += __expf(sp[2] + tr[4 * jj + 2] - M);
                    s3 += __expf(sp[3] + tr[4 * jj + 3] - M);
                }
                pv[ch][kp] = (s0 + s1) + (s2 + s3);
            }
            LGKM_BARRIER();
            int mk = maskS[t];
            int xflag = 0;
            if (tid < 74) {
                float sum = pv[0][tid] + pv[1][tid] + pv[2][tid];
                float nxt = M + __logf(sum) + eA;
                float snew = mk ? nxt : scoreS[cur][tid];
                scoreS[cur ^ 1][tid] = snew;
                xflag = (snew > M + 30.0f) ? 1 : 0;
            }
            int wany = __any(xflag);
            if ((tid & 63) == 0 && tid < 128) flagU[tid >> 6] = wany;
            LGKM_BARRIER();
            cur ^= 1;
            if (flagU[0] | flagU[1]) {          // rare: refresh stabilizer
                float v = (tid < 74) ? scoreS[cur][tid] : -3.0e38f;
                if (tid < 128) {
                    #pragma unroll
                    for (int off = 32; off > 0; off >>= 1) v = fmaxf(v, __shfl_xor(v, off));
                    if ((tid & 63) == 0) Ms[tid >> 6] = v;
                }
                LGKM_BARRIER();
                M = fmaxf(Ms[0], Ms[1]);
            }
            eA = eB; eB = eC;
        }
        if (tid == 0) {
            float m = -3.0e38f;
            for (int k = 0; k < 74; ++k) m = fmaxf(m, scoreS[cur][k] + endv[k]);
            float s = 0.f;
            for (int k = 0; k < 74; ++k) s += __expf(scoreS[cur][k] + endv[k] - m);
            den[b] = m + __logf(s);
        }
    }
}

// ---------------- K6: CRF score per batch, then final reduce
__global__ __launch_bounds__(128) void loss_partial(const float* __restrict__ em,
    const int* __restrict__ labels, const int* __restrict__ mask_,
    const float* __restrict__ startv, const float* __restrict__ endv,
    const float* __restrict__ den, const float* __restrict__ trans, float* __restrict__ nd)
{
    __shared__ float cs[2];
    __shared__ int ms[2];
    int b = blockIdx.x, t = threadIdx.x;
    int lab = labels[b * 128 + t];
    int mk = mask_[b * 128 + t];
    float contrib;
    if (t == 0) {
        contrib = startv[lab] + em[b * 74 + lab];
    } else {
        int labp = labels[b * 128 + t - 1];
        contrib = mk ? (trans[labp * 74 + lab] + em[t * EMS_ + b * 74 + lab]) : 0.f;
    }
    float c = contrib; int m = mk;
    #pragma unroll
    for (int off = 32; off > 0; off >>= 1) {
        c += __shfl_xor(c, off);
        m += __shfl_xor(m, off);
    }
    if ((t & 63) == 0) { cs[t >> 6] = c; ms[t >> 6] = m; }
    __syncthreads();
    if (t == 0) {
        float num = cs[0] + cs[1];
        int msum = ms[0] + ms[1];
        int last = labels[b * 128 + msum - 1];
        num += endv[last];
        nd[b] = num - den[b];
    }
}

__global__ void loss_final(const float* __restrict__ nd, float* __restrict__ out_loss)
{
    __shared__ float red[256];
    int i = threadIdx.x;
    red[i] = nd[i];
    __syncthreads();
    for (int s = 128; s > 0; s >>= 1) { if (i < s) red[i] += red[i + s]; __syncthreads(); }
    if (i == 0) out_loss[0] = -(red[0] / 256.f);
}

extern "C" void kernel_launch(void* const* d_in, const int* in_sizes, int n_in,
                              void* d_out, int out_size, void* d_ws, size_t ws_size,
                              hipStream_t stream)
{
    const float* feats  = (const float*)d_in[0];
    const int*   amask  = (const int*)d_in[1];
    const int*   labels = (const int*)d_in[2];
    const float* cache  = (const float*)d_in[3];
    const float* W1     = (const float*)d_in[4];
    const float* b1     = (const float*)d_in[5];
    const float* W2     = (const float*)d_in[6];
    const float* b2     = (const float*)d_in[7];
    const float* startv = (const float*)d_in[8];
    const float* endv   = (const float*)d_in[9];
    const float* trans  = (const float*)d_in[10];

    float* ws     = (float*)d_ws;
    float* logits = ws;                 // 2,424,832
    float* y      = ws + 2424832;       // 2,424,832
    float* em     = ws + 4849664;       // 2,424,832
    float* part   = ws + 7274496;       // 1,048,576
    float* sim    = ws + 8323072;       // 32,768
    float* p      = ws + 8355840;       // 32,768
    float* den    = ws + 8388608;       // 256
    float* nd     = ws + 8388864;       // 256
    float* W1q    = ws + 8389120;       // 61,440
    float* W2q    = ws + 8450560;       // 5,920
    float* out_tags = (float*)d_out;
    float* out_loss = (float*)d_out + 32768;

    hipLaunchKernelGGL(pad_weights,  dim3(240), dim3(256), 0, stream, W1, W2, W1q, W2q);
    hipLaunchKernelGGL(gemm_logits,  dim3(512), dim3(256), 0, stream, feats, W1q, b1, logits);
    hipLaunchKernelGGL(sim_partial,  dim3(256), dim3(256), 0, stream, logits, cache, part);
    hipLaunchKernelGGL(sim_reduce,   dim3(128), dim3(256), 0, stream, part, sim);
    hipLaunchKernelGGL(softmax128,   dim3(256), dim3(128), 0, stream, sim, p);
    hipLaunchKernelGGL(gemm_h_y,     dim3(592), dim3(256), 0, stream, p, cache, logits, y);
    hipLaunchKernelGGL(gemm_em,      dim3(512), dim3(256), 0, stream, y, W2q, b2, em);
    hipLaunchKernelGGL(crf_scan,     dim3(512), dim3(256), 0, stream, em, amask, startv, endv, trans, out_tags, den);
    hipLaunchKernelGGL(loss_partial, dim3(256), dim3(128), 0, stream, em, labels, amask, startv, endv, den, trans, nd);
    hipLaunchKernelGGL(loss_final,   dim3(1),   dim3(256), 0, stream, nd, out_loss);
}

// Round 6
// 301.959 us; speedup vs baseline: 1.6869x; 1.0515x over previous
//
#include <hip/hip_runtime.h>

#define B_ 256
#define T_ 128
#define D_ 768
#define K_ 74
#define C_ 128
#define TK_ 9472      // T_*K_
#define BT_ 32768     // B_*T_
#define EMS_ 18944    // B_*K_  (em time-slice stride)

#define LGKM_BARRIER() do { \
    asm volatile("s_waitcnt lgkmcnt(0)" ::: "memory"); \
    __builtin_amdgcn_s_barrier(); \
    __builtin_amdgcn_sched_barrier(0); \
} while (0)

// ---------------- K0: pad W1 -> W1q[4][768][20], W2 -> W2q[4][74][20]
__global__ void pad_weights(const float* __restrict__ W1, const float* __restrict__ W2,
                            float* __restrict__ W1q, float* __restrict__ W2q)
{
    int idx = blockIdx.x * 256 + threadIdx.x;
    if (idx < 4 * 768 * 20) {
        int nq = idx / (768 * 20); int rem = idx - nq * (768 * 20);
        int k = rem / 20, j = rem - k * 20;
        int c = nq * 19 + j;
        W1q[idx] = (j < 19 && c < 74) ? W1[k * 74 + c] : 0.f;
    }
    if (idx < 4 * 74 * 20) {
        int nq = idx / (74 * 20); int rem = idx - nq * (74 * 20);
        int k = rem / 20, j = rem - k * 20;
        int c = nq * 19 + j;
        W2q[idx] = (j < 19 && c < 74) ? W2[k * 74 + c] : 0.f;
    }
}

// ---------------- K1: logits = feats @ W1 + b1  (M=32768, N=74, K=768)
__global__ __launch_bounds__(256) void gemm_logits(const float* __restrict__ feats,
    const float* __restrict__ W1q, const float* __restrict__ b1, float* __restrict__ logits)
{
    int orig = blockIdx.x;
    int vb = (orig & 7) * 64 + (orig >> 3);
    int rb = vb >> 2, nq = vb & 3;
    int tid = threadIdx.x;
    int r = rb * 256 + tid;
    int c0 = nq * 19;
    const float* frow = feats + (size_t)r * 768;
    const float* wq = W1q + nq * (768 * 20);
    float acc[20];
    #pragma unroll
    for (int j = 0; j < 20; ++j) acc[j] = 0.f;

    for (int k0 = 0; k0 < 768; k0 += 16) {
        float4 a[4];
        #pragma unroll
        for (int q = 0; q < 4; ++q) a[q] = *(const float4*)(frow + k0 + 4 * q);
        #pragma unroll
        for (int u = 0; u < 16; ++u) {
            float av = ((const float*)a)[u];
            const float* wr = wq + (k0 + u) * 20;
            #pragma unroll
            for (int j = 0; j < 20; ++j) acc[j] += av * wr[j];
        }
    }
    #pragma unroll
    for (int j = 0; j < 19; ++j) {
        int c = c0 + j;
        if (c < 74) logits[(size_t)r * 74 + c] = acc[j] + b1[c];
    }
}

// ---------------- K2: sim partials
__global__ __launch_bounds__(256) void sim_partial(const float* __restrict__ logits,
    const float* __restrict__ cache, float* __restrict__ part)
{
    __shared__ float As[74][68];
    __shared__ float Bs[74][68];
    int tid = threadIdx.x;
    int tx = tid & 15, ty = tid >> 4;
    int bid = blockIdx.x;
    int jc = bid >> 3;
    int mt = (bid >> 1) & 3;
    int nt = bid & 1;
    int p0 = mt * 64, q0 = nt * 64;
    float acc[4][4] = {};
    for (int jj = 0; jj < 4; ++jj) {
        int j = jc * 4 + jj;
        for (int it = 0; it < 19; ++it) {
            int lin = it * 256 + tid;
            if (lin < 64 * 74) {
                int r = lin / 74, ik = lin - r * 74;
                As[ik][r] = logits[(p0 + r) * TK_ + j * 74 + ik];
                Bs[ik][r] = cache[(q0 + r) * TK_ + j * 74 + ik];
            }
        }
        __syncthreads();
        for (int ik = 0; ik < 74; ++ik) {
            float4 a = *(const float4*)&As[ik][4 * tx];
            float4 b = *(const float4*)&Bs[ik][4 * ty];
            const float* ap = (const float*)&a;
            const float* bp = (const float*)&b;
            #pragma unroll
            for (int i = 0; i < 4; ++i)
                #pragma unroll
                for (int q = 0; q < 4; ++q) acc[i][q] += ap[i] * bp[q];
        }
        __syncthreads();
    }
    #pragma unroll
    for (int i = 0; i < 4; ++i)
        #pragma unroll
        for (int q = 0; q < 4; ++q)
            part[jc * (B_ * C_) + (p0 + 4 * tx + i) * C_ + q0 + 4 * ty + q] = acc[i][q];
}

__global__ void sim_reduce(const float* __restrict__ part, float* __restrict__ sim)
{
    int idx = blockIdx.x * 256 + threadIdx.x;
    float s = 0.f;
    for (int jc = 0; jc < 32; ++jc) s += part[jc * (B_ * C_) + idx];
    sim[idx] = s;
}

__global__ void softmax128(const float* __restrict__ sim, float* __restrict__ p)
{
    __shared__ float red[128];
    int q = threadIdx.x, row = blockIdx.x;
    float v = sim[row * 128 + q];
    red[q] = v; __syncthreads();
    for (int s = 64; s > 0; s >>= 1) { if (q < s) red[q] = fmaxf(red[q], red[q + s]); __syncthreads(); }
    float m = red[0]; __syncthreads();
    float e = expf(v - m);
    red[q] = e; __syncthreads();
    for (int s = 64; s > 0; s >>= 1) { if (q < s) red[q] += red[q + s]; __syncthreads(); }
    float sum = red[0];
    p[row * 128 + q] = e / sum;
}

// ---------------- K4a: y = logits + 0.5*(p @ c_r)
__global__ __launch_bounds__(256) void gemm_h_y(const float* __restrict__ pmat,
    const float* __restrict__ cache, const float* __restrict__ logits, float* __restrict__ y)
{
    __shared__ float As[128][68];
    __shared__ float Bs[128][68];
    int tid = threadIdx.x;
    int tx = tid & 15, ty = tid >> 4;
    int mt = blockIdx.x / 148, nt = blockIdx.x - mt * 148;
    int r0 = mt * 64, n0 = nt * 64;
    #pragma unroll
    for (int it = 0; it < 32; ++it) {
        int lin = it * 256 + tid;
        int r = lin >> 7, kk = lin & 127;
        As[kk][r] = pmat[(r0 + r) * 128 + kk];
    }
    #pragma unroll
    for (int it = 0; it < 32; ++it) {
        int lin = it * 256 + tid;
        int kk = lin >> 6, c = lin & 63;
        Bs[kk][c] = cache[kk * TK_ + n0 + c];
    }
    __syncthreads();
    float acc[4][4] = {};
    for (int kk = 0; kk < 128; ++kk) {
        float4 a = *(const float4*)&As[kk][4 * tx];
        float4 b = *(const float4*)&Bs[kk][4 * ty];
        const float* ap = (const float*)&a;
        const float* bp = (const float*)&b;
        #pragma unroll
        for (int i = 0; i < 4; ++i)
            #pragma unroll
            for (int j = 0; j < 4; ++j) acc[i][j] += ap[i] * bp[j];
    }
    #pragma unroll
    for (int i = 0; i < 4; ++i) {
        int r = r0 + 4 * tx + i;
        #pragma unroll
        for (int j = 0; j < 4; ++j) {
            int n = n0 + 4 * ty + j;
            y[r * TK_ + n] = logits[r * TK_ + n] + 0.5f * acc[i][j];
        }
    }
}

// ---------------- K4b: em = (y @ W2 + b2), transposed write
__global__ __launch_bounds__(256) void gemm_em(const float* __restrict__ y,
    const float* __restrict__ W2q, const float* __restrict__ b2, float* __restrict__ em)
{
    int orig = blockIdx.x;
    int vb = (orig & 7) * 64 + (orig >> 3);
    int rb = vb >> 2, nq = vb & 3;
    int tid = threadIdx.x;
    int r = rb * 256 + tid;
    int c0 = nq * 19;
    const float* wq = W2q + nq * (74 * 20);
    const float* yrow = y + (size_t)r * 74;
    float acc[20];
    #pragma unroll
    for (int j = 0; j < 20; ++j) acc[j] = 0.f;
    #pragma unroll 1
    for (int k0 = 0; k0 < 74; k0 += 2) {
        float2 a = *(const float2*)(yrow + k0);
        const float* ap = (const float*)&a;
        #pragma unroll
        for (int u = 0; u < 2; ++u) {
            const float* wr = wq + (k0 + u) * 20;
            #pragma unroll
            for (int j = 0; j < 20; ++j) acc[j] += ap[u] * wr[j];
        }
    }
    int b = r >> 7, t = r & 127;
    #pragma unroll
    for (int j = 0; j < 19; ++j) {
        int c = c0 + j;
        if (c < 74) em[t * EMS_ + b * 74 + c] = acc[j] + b2[c];
    }
}

// ---------------- K5: fused CRF scans. Viterbi as before; normalizer uses the
// exp(trans) factorization: lse_k(s_k + T_kj) = M + log(sum_k exp(s_k-M)*expT_kj).
__global__ __launch_bounds__(256) void crf_scan(const float* __restrict__ em,
    const int* __restrict__ mask_, const float* __restrict__ startv,
    const float* __restrict__ endv, const float* __restrict__ trans,
    float* __restrict__ out_tags, float* __restrict__ den)
{
    __shared__ float transS[74 * 74];
    __shared__ float scoreS[2][88];
    __shared__ float EscS[88] __attribute__((aligned(16)));
    __shared__ float pv[3][74];
    __shared__ int   pi[3][74];
    __shared__ unsigned char histS[127 * 74];
    __shared__ float tagsS[128];
    __shared__ float Ms[2];
    __shared__ int   flagU[2];
    __shared__ int   maskS[128];
    int tid = threadIdx.x;
    bool isV = blockIdx.x < 256;
    int b = isV ? blockIdx.x : (blockIdx.x - 256);

    for (int i = tid; i < 74 * 74; i += 256) transS[i] = trans[i];
    if (tid < 128) maskS[tid] = mask_[b * 128 + tid];
    if (tid >= 74 && tid < 88) { scoreS[0][tid] = -3.0e38f; scoreS[1][tid] = -3.0e38f; EscS[tid] = 0.f; }
    if (tid < 74) scoreS[0][tid] = startv[tid] + em[b * 74 + tid];
    __syncthreads();

    int ch = (tid < 74) ? 0 : (tid < 148 ? 1 : 2);   // 3 chunks of 28 sources
    int kp = tid - ch * 74;                          // dest state
    int cbase = ch * 28;
    float tr[28];
    if (tid < 222) {
        #pragma unroll
        for (int j = 0; j < 28; ++j) {
            int kk = cbase + j;
            tr[j] = (kk < 74) ? transS[kk * 74 + kp] : -1.0e30f;
        }
    }
    int cur = 0;

    // depth-2 em prefetch registers
    float eA = 0.f, eB = 0.f;
    if (tid < 74) {
        eA = em[1 * EMS_ + b * 74 + tid];
        eB = em[2 * EMS_ + b * 74 + tid];
    }

    if (isV) {
        for (int t = 1; t < 128; ++t) {
            float eC = 0.f;
            if (tid < 74 && t + 2 < 128) eC = em[(t + 2) * EMS_ + b * 74 + tid];
            if (tid < 222) {
                float m = -3.0e38f; int mi = cbase;
                #pragma unroll
                for (int jj = 0; jj < 7; ++jj) {
                    float4 s4 = *(const float4*)&scoreS[cur][cbase + 4 * jj];
                    const float* sp = (const float*)&s4;
                    #pragma unroll
                    for (int u = 0; u < 4; ++u) {
                        float v = sp[u] + tr[4 * jj + u];
                        if (v > m) { m = v; mi = cbase + 4 * jj + u; }
                    }
                }
                pv[ch][kp] = m; pi[ch][kp] = mi;
            }
            LGKM_BARRIER();
            int mk = maskS[t];
            if (tid < 74) {
                float m0 = pv[0][tid]; int i0 = pi[0][tid];
                if (pv[1][tid] > m0) { m0 = pv[1][tid]; i0 = pi[1][tid]; }
                if (pv[2][tid] > m0) { m0 = pv[2][tid]; i0 = pi[2][tid]; }
                histS[(t - 1) * 74 + tid] = (unsigned char)i0;
                scoreS[cur ^ 1][tid] = mk ? (m0 + eA) : scoreS[cur][tid];
            }
            LGKM_BARRIER();
            cur ^= 1;
            eA = eB; eB = eC;
        }
        if (tid == 0) {
            float bm = scoreS[cur][0] + endv[0]; int bi = 0;
            for (int k = 1; k < 74; ++k) {
                float v = scoreS[cur][k] + endv[k];
                if (v > bm) { bm = v; bi = k; }
            }
            int curk = bi;
            tagsS[127] = (float)bi;
            for (int ti = 126; ti >= 0; --ti) {
                int mk = maskS[ti + 1];
                curk = mk ? (int)histS[ti * 74 + curk] : bi;
                tagsS[ti] = (float)curk;
            }
        }
        __syncthreads();
        if (tid < 128) out_tags[b * 128 + tid] = tagsS[tid];
    } else {
        // tr regs hold exp(trans); padded -1e30 -> exp = 0 (identity for sums)
        if (tid < 222) {
            #pragma unroll
            for (int j = 0; j < 28; ++j) tr[j] = __expf(tr[j]);
        }
        // exact initial stabilizer M
        float v0 = (tid < 74) ? scoreS[0][tid] : -3.0e38f;
        float M;
        if (tid < 128) {
            #pragma unroll
            for (int off = 32; off > 0; off >>= 1) v0 = fmaxf(v0, __shfl_xor(v0, off));
            if ((tid & 63) == 0) Ms[tid >> 6] = v0;
        }
        __syncthreads();
        M = fmaxf(Ms[0], Ms[1]);
        if (tid < 74) EscS[tid] = __expf(scoreS[0][tid] - M);
        LGKM_BARRIER();
        for (int t = 1; t < 128; ++t) {
            float eC = 0.f;
            if (tid < 74 && t + 2 < 128) eC = em[(t + 2) * EMS_ + b * 74 + tid];
            if (tid < 222) {
                float s0 = 0.f, s1 = 0.f, s2 = 0.f, s3 = 0.f;
                #pragma unroll
                for (int jj = 0; jj < 7; ++jj) {
                    float4 E4 = *(const float4*)&EscS[cbase + 4 * jj];
                    s0 += E4.x * tr[4 * jj + 0];
                    s1 += E4.y * tr[4 * jj + 1];
                    s2 += E4.z * tr[4 * jj + 2];
                    s3 += E4.w * tr[4 * jj + 3];
                }
                pv[ch][kp] = (s0 + s1) + (s2 + s3);
            }
            LGKM_BARRIER();
            int mk = maskS[t];
            int over = 0, notunder = 0;
            float snew = 0.f;
            if (tid < 74) {
                float sum = pv[0][tid] + pv[1][tid] + pv[2][tid];
                float nxt = M + __logf(sum) + eA;
                snew = mk ? nxt : scoreS[cur][tid];
                scoreS[cur ^ 1][tid] = snew;
                EscS[tid] = __expf(snew - M);            // valid unless refresh below
                over = (snew > M + 55.0f) ? 1 : 0;
                notunder = (snew >= M - 40.0f) ? 1 : 0;
            }
            int refresh = __any(over) | (!__any(notunder));   // per-wave; waves 2,3 masked out below
            if ((tid & 63) == 0 && tid < 128) flagU[tid >> 6] = refresh;
            LGKM_BARRIER();
            cur ^= 1;
            if (flagU[0] | flagU[1]) {          // occasional: refresh stabilizer + E
                float v = (tid < 74) ? scoreS[cur][tid] : -3.0e38f;
                if (tid < 128) {
                    #pragma unroll
                    for (int off = 32; off > 0; off >>= 1) v = fmaxf(v, __shfl_xor(v, off));
                    if ((tid & 63) == 0) Ms[tid >> 6] = v;
                }
                LGKM_BARRIER();
                M = fmaxf(Ms[0], Ms[1]);
                if (tid < 74) EscS[tid] = __expf(scoreS[cur][tid] - M);
                LGKM_BARRIER();
            }
            eA = eB; eB = eC;
        }
        if (tid == 0) {
            float m = -3.0e38f;
            for (int k = 0; k < 74; ++k) m = fmaxf(m, scoreS[cur][k] + endv[k]);
            float s = 0.f;
            for (int k = 0; k < 74; ++k) s += __expf(scoreS[cur][k] + endv[k] - m);
            den[b] = m + __logf(s);
        }
    }
}

// ---------------- K6: CRF score per batch, then final reduce
__global__ __launch_bounds__(128) void loss_partial(const float* __restrict__ em,
    const int* __restrict__ labels, const int* __restrict__ mask_,
    const float* __restrict__ startv, const float* __restrict__ endv,
    const float* __restrict__ den, const float* __restrict__ trans, float* __restrict__ nd)
{
    __shared__ float cs[2];
    __shared__ int ms[2];
    int b = blockIdx.x, t = threadIdx.x;
    int lab = labels[b * 128 + t];
    int mk = mask_[b * 128 + t];
    float contrib;
    if (t == 0) {
        contrib = startv[lab] + em[b * 74 + lab];
    } else {
        int labp = labels[b * 128 + t - 1];
        contrib = mk ? (trans[labp * 74 + lab] + em[t * EMS_ + b * 74 + lab]) : 0.f;
    }
    float c = contrib; int m = mk;
    #pragma unroll
    for (int off = 32; off > 0; off >>= 1) {
        c += __shfl_xor(c, off);
        m += __shfl_xor(m, off);
    }
    if ((t & 63) == 0) { cs[t >> 6] = c; ms[t >> 6] = m; }
    __syncthreads();
    if (t == 0) {
        float num = cs[0] + cs[1];
        int msum = ms[0] + ms[1];
        int last = labels[b * 128 + msum - 1];
        num += endv[last];
        nd[b] = num - den[b];
    }
}

__global__ void loss_final(const float* __restrict__ nd, float* __restrict__ out_loss)
{
    __shared__ float red[256];
    int i = threadIdx.x;
    red[i] = nd[i];
    __syncthreads();
    for (int s = 128; s > 0; s >>= 1) { if (i < s) red[i] += red[i + s]; __syncthreads(); }
    if (i == 0) out_loss[0] = -(red[0] / 256.f);
}

extern "C" void kernel_launch(void* const* d_in, const int* in_sizes, int n_in,
                              void* d_out, int out_size, void* d_ws, size_t ws_size,
                              hipStream_t stream)
{
    const float* feats  = (const float*)d_in[0];
    const int*   amask  = (const int*)d_in[1];
    const int*   labels = (const int*)d_in[2];
    const float* cache  = (const float*)d_in[3];
    const float* W1     = (const float*)d_in[4];
    const float* b1     = (const float*)d_in[5];
    const float* W2     = (const float*)d_in[6];
    const float* b2     = (const float*)d_in[7];
    const float* startv = (const float*)d_in[8];
    const float* endv   = (const float*)d_in[9];
    const float* trans  = (const float*)d_in[10];

    float* ws     = (float*)d_ws;
    float* logits = ws;                 // 2,424,832
    float* y      = ws + 2424832;       // 2,424,832
    float* em     = ws + 4849664;       // 2,424,832
    float* part   = ws + 7274496;       // 1,048,576
    float* sim    = ws + 8323072;       // 32,768
    float* p      = ws + 8355840;       // 32,768
    float* den    = ws + 8388608;       // 256
    float* nd     = ws + 8388864;       // 256
    float* W1q    = ws + 8389120;       // 61,440
    float* W2q    = ws + 8450560;       // 5,920
    float* out_tags = (float*)d_out;
    float* out_loss = (float*)d_out + 32768;

    hipLaunchKernelGGL(pad_weights,  dim3(240), dim3(256), 0, stream, W1, W2, W1q, W2q);
    hipLaunchKernelGGL(gemm_logits,  dim3(512), dim3(256), 0, stream, feats, W1q, b1, logits);
    hipLaunchKernelGGL(sim_partial,  dim3(256), dim3(256), 0, stream, logits, cache, part);
    hipLaunchKernelGGL(sim_reduce,   dim3(128), dim3(256), 0, stream, part, sim);
    hipLaunchKernelGGL(softmax128,   dim3(256), dim3(128), 0, stream, sim, p);
    hipLaunchKernelGGL(gemm_h_y,     dim3(592), dim3(256), 0, stream, p, cache, logits, y);
    hipLaunchKernelGGL(gemm_em,      dim3(512), dim3(256), 0, stream, y, W2q, b2, em);
    hipLaunchKernelGGL(crf_scan,     dim3(512), dim3(256), 0, stream, em, amask, startv, endv, trans, out_tags, den);
    hipLaunchKernelGGL(loss_partial, dim3(256), dim3(128), 0, stream, em, labels, amask, startv, endv, den, trans, nd);
    hipLaunchKernelGGL(loss_final,   dim3(1),   dim3(256), 0, stream, nd, out_loss);
}